// Round 8
// baseline (246.651 us; speedup 1.0000x reference)
//
#include <hip/hip_runtime.h>
#include <math.h>

#define S_LEN 1024
#define NH 8

typedef __attribute__((ext_vector_type(8))) short bf16x8;
typedef __attribute__((ext_vector_type(4))) float f32x4;

__device__ __forceinline__ float sp_softplus(float x) {
    return fmaxf(x, 0.f) + log1pf(expf(-fabsf(x)));
}

__device__ __forceinline__ unsigned short bfu(float f) {
    unsigned u = __float_as_uint(f);
    unsigned r = (u + 0x7FFFu + ((u >> 16) & 1u)) >> 16;   // RNE
    return (unsigned short)r;
}

// ============ fp32 routed GEMM w/ split-K (SELECTION PATH ONLY) ==============
struct MGK {
    const float* A[4]; const float* B[4]; float* Cw[4];
    int lda[4], ldb[4], wldc[4], K[4], N[4], KS[4], ntiles[4];
    long pstride[4];
    int ustart[5]; int ne;
};

__global__ __launch_bounds__(128) void gemmk(MGK mg)
{
    int u = blockIdx.x;
    int e = 0;
    #pragma unroll
    for (int i = 1; i < 4; ++i) if (i < mg.ne && u >= mg.ustart[i]) e = i;
    int local = u - mg.ustart[e];
    int nt = local % mg.ntiles[e];
    int ks = local / mg.ntiles[e];
    const float* A = mg.A[e];
    const float* B = mg.B[e];
    int lda = mg.lda[e], ldb = mg.ldb[e], ldc = mg.wldc[e];
    int N = mg.N[e];
    int kb = ks * (mg.K[e] / mg.KS[e]);
    int ke = kb + mg.K[e] / mg.KS[e];
    float* C = mg.Cw[e] + ks * mg.pstride[e];
    int m0 = blockIdx.y * 16, n0 = nt * 64;

    __shared__ float As[16][18];
    __shared__ float Bs[16][68];
    int t = threadIdx.x;
    int ar = t >> 2, ak = t & 3;
    int bk = t >> 3, bn = t & 7;
    int ty = t >> 4, tx = t & 15;
    bool ok0 = (n0 + bn * 4) < N;
    bool ok1 = (n0 + (bn + 8) * 4) < N;

    float4 aN = make_float4(0.f, 0.f, 0.f, 0.f);
    if (t < 64) aN = *(const float4*)(A + (long)(m0 + ar) * lda + kb + ak * 4);
    float4 b0 = ok0 ? *(const float4*)(B + (long)(kb + bk) * ldb + n0 + bn * 4)
                    : make_float4(0.f, 0.f, 0.f, 0.f);
    float4 b1 = ok1 ? *(const float4*)(B + (long)(kb + bk) * ldb + n0 + (bn + 8) * 4)
                    : make_float4(0.f, 0.f, 0.f, 0.f);
    float acc[2][4] = {};
    for (int k0 = kb; k0 < ke; k0 += 16) {
        if (t < 64) {
            As[ak * 4 + 0][ar] = aN.x;
            As[ak * 4 + 1][ar] = aN.y;
            As[ak * 4 + 2][ar] = aN.z;
            As[ak * 4 + 3][ar] = aN.w;
        }
        *(float4*)&Bs[bk][bn * 4] = b0;
        *(float4*)&Bs[bk][(bn + 8) * 4] = b1;
        __syncthreads();
        if (k0 + 16 < ke) {
            if (t < 64) aN = *(const float4*)(A + (long)(m0 + ar) * lda + (k0 + 16) + ak * 4);
            b0 = ok0 ? *(const float4*)(B + (long)(k0 + 16 + bk) * ldb + n0 + bn * 4)
                     : make_float4(0.f, 0.f, 0.f, 0.f);
            b1 = ok1 ? *(const float4*)(B + (long)(k0 + 16 + bk) * ldb + n0 + (bn + 8) * 4)
                     : make_float4(0.f, 0.f, 0.f, 0.f);
        }
        #pragma unroll
        for (int kk = 0; kk < 16; ++kk) {
            float2 a = *(float2*)&As[kk][ty * 2];
            float4 b = *(float4*)&Bs[kk][tx * 4];
            acc[0][0] += a.x * b.x; acc[0][1] += a.x * b.y;
            acc[0][2] += a.x * b.z; acc[0][3] += a.x * b.w;
            acc[1][0] += a.y * b.x; acc[1][1] += a.y * b.y;
            acc[1][2] += a.y * b.z; acc[1][3] += a.y * b.w;
        }
        __syncthreads();
    }
    if ((n0 + tx * 4) < N) {
        #pragma unroll
        for (int i = 0; i < 2; ++i) {
            float4 v = make_float4(acc[i][0], acc[i][1], acc[i][2], acc[i][3]);
            *(float4*)(C + (long)(m0 + ty * 2 + i) * ldc + n0 + tx * 4) = v;
        }
    }
}

// ============ bf16 MFMA routed multi-GEMM (VALUE PATH) =======================
struct MFG {
    const float* A[10]; const unsigned short* B[10]; float* C[10];
    int lda[10], ldb[10], ldc[10], K[10], N[10];
    int tstart[11]; int ne;
};

__global__ __launch_bounds__(256) void mgemm(MFG mg)
{
    int bx = blockIdx.x, e = 0;
    #pragma unroll
    for (int i = 1; i < 10; ++i) if (i < mg.ne && bx >= mg.tstart[i]) e = i;
    const float* A = mg.A[e];
    const unsigned short* B = mg.B[e];
    float* C = mg.C[e];
    int lda = mg.lda[e], ldb = mg.ldb[e], ldc = mg.ldc[e];
    int K = mg.K[e], N = mg.N[e];
    int m0 = blockIdx.y * 64, n0 = (bx - mg.tstart[e]) * 64;

    __shared__ unsigned short As[64][40];
    __shared__ unsigned short Bs[64][40];
    int t = threadIdx.x;
    int srow = t >> 2, skq = t & 3;
    int wid = t >> 6, l = t & 63;
    int wm = (wid >> 1) * 32, wn = (wid & 1) * 32;
    int fr = l & 15, fk = (l >> 4) * 8;
    bool bok = (n0 + srow) < N;

    f32x4 acc00 = {0.f, 0.f, 0.f, 0.f};
    f32x4 acc01 = {0.f, 0.f, 0.f, 0.f};
    f32x4 acc10 = {0.f, 0.f, 0.f, 0.f};
    f32x4 acc11 = {0.f, 0.f, 0.f, 0.f};

    for (int k0 = 0; k0 < K; k0 += 32) {
        {
            const float* ap = A + (long)(m0 + srow) * lda + k0 + skq * 8;
            float4 v0 = *(const float4*)ap;
            float4 v1 = *(const float4*)(ap + 4);
            unsigned short* d = &As[srow][skq * 8];
            d[0] = bfu(v0.x); d[1] = bfu(v0.y); d[2] = bfu(v0.z); d[3] = bfu(v0.w);
            d[4] = bfu(v1.x); d[5] = bfu(v1.y); d[6] = bfu(v1.z); d[7] = bfu(v1.w);
        }
        {
            uint4 bv = make_uint4(0u, 0u, 0u, 0u);
            if (bok) bv = *(const uint4*)(B + (long)(n0 + srow) * ldb + k0 + skq * 8);
            *(uint4*)&Bs[srow][skq * 8] = bv;
        }
        __syncthreads();
        bf16x8 a0 = *(bf16x8*)&As[wm + fr][fk];
        bf16x8 a1 = *(bf16x8*)&As[wm + 16 + fr][fk];
        bf16x8 b0 = *(bf16x8*)&Bs[wn + fr][fk];
        bf16x8 b1 = *(bf16x8*)&Bs[wn + 16 + fr][fk];
        acc00 = __builtin_amdgcn_mfma_f32_16x16x32_bf16(a0, b0, acc00, 0, 0, 0);
        acc01 = __builtin_amdgcn_mfma_f32_16x16x32_bf16(a0, b1, acc01, 0, 0, 0);
        acc10 = __builtin_amdgcn_mfma_f32_16x16x32_bf16(a1, b0, acc10, 0, 0, 0);
        acc11 = __builtin_amdgcn_mfma_f32_16x16x32_bf16(a1, b1, acc11, 0, 0, 0);
        __syncthreads();
    }
    int crow = (l >> 4) * 4;
    int col0 = n0 + wn + fr, col1 = n0 + wn + 16 + fr;
    if (col0 < N) {
        #pragma unroll
        for (int r = 0; r < 4; ++r) {
            C[(long)(m0 + wm + crow + r) * ldc + col0]      = acc00[r];
            C[(long)(m0 + wm + 16 + crow + r) * ldc + col0] = acc10[r];
        }
    }
    if (col1 < N) {
        #pragma unroll
        for (int r = 0; r < 4; ++r) {
            C[(long)(m0 + wm + crow + r) * ldc + col1]      = acc01[r];
            C[(long)(m0 + wm + 16 + crow + r) * ldc + col1] = acc11[r];
        }
    }
}

// ---- tiled transpose+cast: src fp32 [K][N] -> dst bf16 [N][K] ---------------
struct TC8 {
    const float* src[8]; unsigned short* dst[8];
    int N[8], Kld[8], Ntiles[8];
    int bstart[9]; int ne;
};
__global__ __launch_bounds__(256) void tcast(TC8 tc)
{
    int b = blockIdx.x, e = 0;
    #pragma unroll
    for (int i = 1; i < 8; ++i) if (i < tc.ne && b >= tc.bstart[i]) e = i;
    int lb = b - tc.bstart[e];
    int nt = lb % tc.Ntiles[e], kt = lb / tc.Ntiles[e];
    const float* src = tc.src[e];
    unsigned short* dst = tc.dst[e];
    int N = tc.N[e], Kld = tc.Kld[e];
    int k0 = kt * 64, n0 = nt * 64;
    __shared__ unsigned short tile[64][65];
    int t = threadIdx.x;
    int c = t & 63, r4 = t >> 6;
    #pragma unroll
    for (int it = 0; it < 16; ++it) {
        int r = it * 4 + r4;
        float v = (n0 + c < N) ? src[(long)(k0 + r) * N + n0 + c] : 0.f;
        tile[r][c] = bfu(v);
    }
    __syncthreads();
    int wq = t & 7;
    #pragma unroll
    for (int itw = 0; itw < 2; ++itw) {
        int wr = itw * 32 + (t >> 3);
        if (n0 + wr < N) {
            unsigned short v[8];
            #pragma unroll
            for (int j = 0; j < 8; ++j) v[j] = tile[wq * 8 + j][wr];
            *(uint4*)(dst + (long)(n0 + wr) * Kld + k0 + wq * 8) = *(uint4*)v;
        }
    }
}

// ---- small prep: mu = softplus(xkr); key-PoPE cos/sin; w_uk cast ------------
__global__ __launch_bounds__(256) void prep_small(
    const float* __restrict__ xkr, const float* __restrict__ raw_delta,
    const float* __restrict__ w_uk,
    float* __restrict__ mu, float* __restrict__ csc, float* __restrict__ css,
    unsigned short* __restrict__ wukb)
{
    int b = blockIdx.x, tid = threadIdx.x;
    if (b < 128) {
        int i = b * 256 + tid;
        mu[i] = sp_softplus(xkr[i]);
    } else if (b < 136) {
        int idx = (b - 128) * 256 + tid;
        int j = idx >> 4, i = idx & 15;
        float rd = raw_delta[i];
        float delta = -6.283185307179586f * (1.f / (1.f + expf(-rd)));
        float th = exp2f(-(float)i * 0.83048202372184f);
        float ang = (float)j * th + delta;
        float sv, cv;
        sincosf(ang, &sv, &cv);
        csc[idx] = cv;
        css[idx] = sv;
    } else {
        int idx = (b - 136) * 256 + tid;
        wukb[idx] = bfu(w_uk[idx]);
    }
}

// ---------------- PoPE for queries (unchanged) --------------------------------
__global__ __launch_bounds__(128) void pope_q_kernel(
    const float* __restrict__ pre, const float* __restrict__ raw_delta,
    float* __restrict__ outq)
{
    int t = blockIdx.x, tid = threadIdx.x;
    int h = tid >> 4, i = tid & 15;
    float rd = raw_delta[i];
    float delta = -6.283185307179586f * (1.f / (1.f + expf(-rd)));
    float th = exp2f(-(float)i * 0.83048202372184f);
    float ang = (float)t * th + delta;
    float sv, cv;
    sincosf(ang, &sv, &cv);
    float m1 = sp_softplus(pre[t * 256 + h * 32 + i]);
    float m2 = sp_softplus(pre[t * 256 + h * 32 + 16 + i]);
    outq[t * 256 + h * 32 + i]      = m1 * cv - m2 * sv;
    outq[t * 256 + h * 32 + 16 + i] = m1 * sv + m2 * cv;
}

// -------- lightning indexer w/ fused split-K reduce (4 qI slabs, 8 kI slabs) --
__global__ __launch_bounds__(256) void indexer_kernel(
    const float* __restrict__ qIP, const float* __restrict__ kIP,
    const float* __restrict__ w_idx, float* __restrict__ I)
{
    int sb = blockIdx.x, tb = blockIdx.y;
    if (sb * 64 > tb * 32 + 31) return;
    int t0 = tb * 32, s0 = sb * 64;
    __shared__ float ksT[64][68];
    __shared__ float qs[32][68];
    int t = threadIdx.x;
    {
        int r = t & 63, q = t >> 6;
        #pragma unroll
        for (int u = 0; u < 4; ++u) {
            int c4 = q * 4 + u;
            long off = (long)(s0 + r) * 64 + c4 * 4;
            float4 v = *(const float4*)(kIP + off);
            #pragma unroll
            for (int s = 1; s < 8; ++s) {
                float4 v2 = *(const float4*)(kIP + (long)s * 65536 + off);
                v.x += v2.x; v.y += v2.y; v.z += v2.z; v.w += v2.w;
            }
            ksT[c4 * 4 + 0][r] = v.x;
            ksT[c4 * 4 + 1][r] = v.y;
            ksT[c4 * 4 + 2][r] = v.z;
            ksT[c4 * 4 + 3][r] = v.w;
        }
    }
    int ty = t >> 4, tx = t & 15;
    float accI[2][4] = {};
    for (int h = 0; h < 8; ++h) {
        __syncthreads();
        {
            int r = t >> 3, q = t & 7;
            long base = (long)(t0 + r) * 512 + h * 64;
            #pragma unroll
            for (int half = 0; half < 2; ++half) {
                long off = base + (q + half * 8) * 4;
                float4 a = *(const float4*)(qIP + off);
                #pragma unroll
                for (int s = 1; s < 4; ++s) {
                    float4 a1 = *(const float4*)(qIP + (long)s * 524288 + off);
                    a.x += a1.x; a.y += a1.y; a.z += a1.z; a.w += a1.w;
                }
                *(float4*)&qs[r][(q + half * 8) * 4] = a;
            }
        }
        __syncthreads();
        float acc[2][4] = {};
        #pragma unroll
        for (int dc = 0; dc < 4; ++dc) {
            float a0[16], a1[16];
            #pragma unroll
            for (int u = 0; u < 4; ++u) {
                float4 v0 = *(float4*)&qs[ty * 2][dc * 16 + u * 4];
                float4 v1 = *(float4*)&qs[ty * 2 + 1][dc * 16 + u * 4];
                a0[u * 4 + 0] = v0.x; a0[u * 4 + 1] = v0.y; a0[u * 4 + 2] = v0.z; a0[u * 4 + 3] = v0.w;
                a1[u * 4 + 0] = v1.x; a1[u * 4 + 1] = v1.y; a1[u * 4 + 2] = v1.z; a1[u * 4 + 3] = v1.w;
            }
            #pragma unroll
            for (int kk = 0; kk < 16; ++kk) {
                int d = dc * 16 + kk;
                float4 b = *(float4*)&ksT[d][tx * 4];
                acc[0][0] += a0[kk] * b.x; acc[0][1] += a0[kk] * b.y;
                acc[0][2] += a0[kk] * b.z; acc[0][3] += a0[kk] * b.w;
                acc[1][0] += a1[kk] * b.x; acc[1][1] += a1[kk] * b.y;
                acc[1][2] += a1[kk] * b.z; acc[1][3] += a1[kk] * b.w;
            }
        }
        float wh = w_idx[h];
        #pragma unroll
        for (int i = 0; i < 2; ++i)
            #pragma unroll
            for (int j = 0; j < 4; ++j)
                accI[i][j] += wh * fmaxf(acc[i][j], 0.f);
    }
    #pragma unroll
    for (int i = 0; i < 2; ++i) {
        float4 v = make_float4(accI[i][0], accI[i][1], accI[i][2], accI[i][3]);
        *(float4*)&I[(long)(t0 + ty * 2 + i) * 1024 + s0 + tx * 4] = v;
    }
}

// -------- exact top-k (unchanged) ---------------------------------------------
__global__ __launch_bounds__(256) void topk_kernel(
    const float* __restrict__ I, int* __restrict__ idxout)
{
    int t = blockIdx.x * 4 + (threadIdx.x >> 6);
    int lane = threadIdx.x & 63;
    int smin = max(0, t - 63);
    int w = min(64, t + 1);
    if (lane < w) idxout[t * 128 + lane] = smin + lane;
    for (int q = t + 1 + lane; q < 128; q += 64)
        idxout[t * 128 + q] = q;
    int f = max(0, t - 63);
    int m = min(f, 64);
    if (m == 0) return;
    const float* row = I + (long)t * 1024;
    unsigned long long key[16];
    #pragma unroll
    for (int i = 0; i < 16; ++i) {
        int s = i * 64 + lane;
        key[i] = 0ull;
        if (s < f) {
            unsigned u = __float_as_uint(row[s]);
            unsigned ou = (u & 0x80000000u) ? ~u : (u | 0x80000000u);
            key[i] = ((unsigned long long)ou << 32) | (0xFFFFFFFFu - (unsigned)s);
        }
    }
    for (int it = 0; it < m; ++it) {
        unsigned long long best = key[0];
        #pragma unroll
        for (int i = 1; i < 16; ++i) best = key[i] > best ? key[i] : best;
        #pragma unroll
        for (int off = 32; off > 0; off >>= 1) {
            unsigned long long o = __shfl_xor(best, off, 64);
            best = o > best ? o : best;
        }
        int s = (int)(0xFFFFFFFFu - (unsigned)(best & 0xFFFFFFFFull));
        if (lane == 0) idxout[t * 128 + w + it] = s;
        if ((s & 63) == lane) {
            int slot = s >> 6;
            #pragma unroll
            for (int i = 0; i < 16; ++i)
                if (i == slot) key[i] = 0ull;
        }
    }
}

// -------- fused attention v5: MFMA QK^T, bf16 K/V in LDS, flash over 2x64 -----
// 256 threads (4 waves), block per query t. LDS ~50 KB -> 3 blocks/CU.
// S^T[slot][h] = mfma(A=K-rows, B=Q-rows): C col=lane&15 (=h), row=(lane>>4)*4+r
// (=slot-in-tile) — same verified layout as mgemm. PV on VALU from bf16 LDS.
__global__ __launch_bounds__(256) void attn_kernel(
    const float* __restrict__ qabs, const float* __restrict__ qrr,
    const float* __restrict__ ckv, const float* __restrict__ mu,
    const float* __restrict__ csc, const float* __restrict__ css,
    const int* __restrict__ idxb, float* __restrict__ olat)
{
    __shared__ unsigned short kv[64][296];   // cols 0..255 ckv, 256..287 kr
    __shared__ unsigned short Qb[16][296];   // rows 0..7 = scaled Q, 8..15 = 0
    __shared__ float sc[8][68];
    __shared__ int idx_s[128];

    int t = blockIdx.x, tid = threadIdx.x;
    int w = tid >> 6, l = tid & 63;
    const float scale = 0.10206207261596575f;

    if (tid < 128) idx_s[tid] = idxb[t * 128 + tid];
    {   // stage Qb: rows r (0..7) from qabs/qrr, rows r+8 zero
        int r = tid >> 5;
        for (int c = tid & 31; c < 296; c += 32) {
            float v = 0.f;
            if (c < 256)      v = qabs[(long)t * 2048 + r * 256 + c] * scale;
            else if (c < 288) v = qrr[(long)t * 256 + r * 32 + (c - 256)] * scale;
            Qb[r][c] = bfu(v);
            Qb[r + 8][c] = 0;
        }
    }
    __syncthreads();

    // hoist Q B-frags to regs (constant across chunks)
    bf16x8 qf[9];
    #pragma unroll
    for (int ks = 0; ks < 9; ++ks)
        qf[ks] = *(bf16x8*)&Qb[l & 15][ks * 32 + (l >> 4) * 8];

    float mrun0 = -INFINITY, mrun1 = -INFINITY;
    float lrun0 = 0.f, lrun1 = 0.f;
    float acc0 = 0, acc1 = 0, acc2 = 0, acc3 = 0;
    float acc4 = 0, acc5 = 0, acc6 = 0, acc7 = 0;

    int sr = tid >> 2, sq = tid & 3;     // staging: row, quarter
    int hme = 2 * w + (l >> 5);          // PV: this lane's head
    int c8 = (l & 31) * 8;               // PV: this lane's c-octet

    #pragma unroll
    for (int chunk = 0; chunk < 2; ++chunk) {
        __syncthreads();   // prev chunk's PV done reading kv
        {   // stage ckv rows -> bf16 (thread covers cols sq*64..sq*64+63)
            int src = idx_s[chunk * 64 + sr];
            const float4* sp4 = (const float4*)(ckv + (long)src * 256) + sq * 16;
            #pragma unroll
            for (int g = 0; g < 8; ++g) {
                float4 v0 = sp4[g * 2];
                float4 v1 = sp4[g * 2 + 1];
                unsigned short hh[8];
                hh[0] = bfu(v0.x); hh[1] = bfu(v0.y); hh[2] = bfu(v0.z); hh[3] = bfu(v0.w);
                hh[4] = bfu(v1.x); hh[5] = bfu(v1.y); hh[6] = bfu(v1.z); hh[7] = bfu(v1.w);
                *(uint4*)&kv[sr][sq * 64 + g * 8] = *(uint4*)hh;
            }
        }
        {   // stage kr cols (PoPE at pos = global slot)
            int src = idx_s[chunk * 64 + sr];
            int j = chunk * 64 + sr;
            unsigned short hh[8];
            #pragma unroll
            for (int ii = 0; ii < 8; ++ii) {
                int i = sq * 8 + ii;
                int i15 = i & 15;
                float m1 = mu[src * 32 + i15];
                float m2 = mu[src * 32 + 16 + i15];
                float cv = csc[j * 16 + i15];
                float sv = css[j * 16 + i15];
                float kr = (i < 16) ? (m1 * cv - m2 * sv) : (m1 * sv + m2 * cv);
                hh[ii] = bfu(kr);
            }
            *(uint4*)&kv[sr][256 + sq * 8] = *(uint4*)hh;
        }
        __syncthreads();

        // QK^T via MFMA: wave w -> slot tile w*16..w*16+15
        f32x4 st = {0.f, 0.f, 0.f, 0.f};
        #pragma unroll
        for (int ks = 0; ks < 9; ++ks) {
            bf16x8 af = *(bf16x8*)&kv[w * 16 + (l & 15)][ks * 32 + (l >> 4) * 8];
            st = __builtin_amdgcn_mfma_f32_16x16x32_bf16(af, qf[ks], st, 0, 0, 0);
        }
        {   // scatter S^T to sc[h][slot] (h<8 only)
            int hcol = l & 15;
            int srow = w * 16 + (l >> 4) * 4;
            if (hcol < 8) {
                #pragma unroll
                for (int r = 0; r < 4; ++r) sc[hcol][srow + r] = st[r];
            }
        }
        __syncthreads();

        // online softmax: wave w handles heads 2w, 2w+1 (full 64 lanes each)
        float rh0, rh1;
        {
            int h = 2 * w;
            float v = sc[h][l];
            float mx = v;
            #pragma unroll
            for (int off = 32; off > 0; off >>= 1) mx = fmaxf(mx, __shfl_xor(mx, off));
            float mnew = fmaxf(mrun0, mx);
            float p = expf(v - mnew);
            float ps = p;
            #pragma unroll
            for (int off = 32; off > 0; off >>= 1) ps += __shfl_xor(ps, off);
            rh0 = expf(mrun0 - mnew);
            lrun0 = lrun0 * rh0 + ps;
            mrun0 = mnew;
            sc[h][l] = p;
        }
        {
            int h = 2 * w + 1;
            float v = sc[h][l];
            float mx = v;
            #pragma unroll
            for (int off = 32; off > 0; off >>= 1) mx = fmaxf(mx, __shfl_xor(mx, off));
            float mnew = fmaxf(mrun1, mx);
            float p = expf(v - mnew);
            float ps = p;
            #pragma unroll
            for (int off = 32; off > 0; off >>= 1) ps += __shfl_xor(ps, off);
            rh1 = expf(mrun1 - mnew);
            lrun1 = lrun1 * rh1 + ps;
            mrun1 = mnew;
            sc[h][l] = p;
        }
        float rsel = (l >> 5) ? rh1 : rh0;
        acc0 *= rsel; acc1 *= rsel; acc2 *= rsel; acc3 *= rsel;
        acc4 *= rsel; acc5 *= rsel; acc6 *= rsel; acc7 *= rsel;

        // PV (VALU): lane owns head hme, c-octet c8
        #pragma unroll 4
        for (int j = 0; j < 64; ++j) {
            float p = sc[hme][j];
            uint4 vv = *(uint4*)&kv[j][c8];
            acc0 += p * __uint_as_float(vv.x << 16);
            acc1 += p * __uint_as_float(vv.x & 0xffff0000u);
            acc2 += p * __uint_as_float(vv.y << 16);
            acc3 += p * __uint_as_float(vv.y & 0xffff0000u);
            acc4 += p * __uint_as_float(vv.z << 16);
            acc5 += p * __uint_as_float(vv.z & 0xffff0000u);
            acc6 += p * __uint_as_float(vv.w << 16);
            acc7 += p * __uint_as_float(vv.w & 0xffff0000u);
        }
    }

    float lr = (l >> 5) ? lrun1 : lrun0;
    float inv = 1.f / lr;
    float* op = olat + (long)t * 2048 + hme * 256 + c8;
    *(float4*)op       = make_float4(acc0 * inv, acc1 * inv, acc2 * inv, acc3 * inv);
    *(float4*)(op + 4) = make_float4(acc4 * inv, acc5 * inv, acc6 * inv, acc7 * inv);
}

extern "C" void kernel_launch(void* const* d_in, const int* in_sizes, int n_in,
                              void* d_out, int out_size, void* d_ws, size_t ws_size,
                              hipStream_t stream)
{
    const float* x         = (const float*)d_in[0];
    const float* w_q_idx   = (const float*)d_in[1];
    const float* w_k_idx   = (const float*)d_in[2];
    const float* w_idx     = (const float*)d_in[3];
    const float* raw_delta = (const float*)d_in[4];
    const float* w_dkv     = (const float*)d_in[5];
    const float* w_uk      = (const float*)d_in[6];
    const float* w_uv      = (const float*)d_in[7];
    const float* w_dq      = (const float*)d_in[8];
    const float* w_uq      = (const float*)d_in[9];
    const float* w_qr      = (const float*)d_in[10];
    const float* w_kr      = (const float*)d_in[11];
    const float* w_out     = (const float*)d_in[12];
    (void)in_sizes; (void)n_in; (void)out_size; (void)ws_size;
    float* out = (float*)d_out;

    float* ws = (float*)d_ws;
    float* ckv   = ws;        ws += 1024 * 256;
    float* cq    = ws;        ws += 1024 * 512;
    float* xkr   = ws;        ws += 1024 * 32;
    float* qrp   = ws;        ws += 1024 * 256;
    float* qrr   = ws;        ws += 1024 * 256;
    float* qc    = ws;        ws += 1024 * 512;
    float* qabs  = ws;        ws += 1024 * 2048;
    float* Ibuf  = ws;        ws += 1024 * 1024;
    int*   idxb  = (int*)ws;  ws += 1024 * 128;
    float* olat  = ws;        ws += 1024 * 2048;
    float* outh  = ws;        ws += 1024 * 512;
    float* mu    = ws;        ws += 1024 * 32;
    float* cscb  = ws;        ws += 128 * 16;
    float* cssb  = ws;        ws += 128 * 16;
    unsigned short* wdkvT = (unsigned short*)ws;  ws += 131072;
    unsigned short* wdqT  = (unsigned short*)ws;  ws += 262144;
    unsigned short* wkrT  = (unsigned short*)ws;  ws += 16384;
    unsigned short* wuqT  = (unsigned short*)ws;  ws += 131072;
    unsigned short* wqrT  = (unsigned short*)ws;  ws += 65536;
    unsigned short* wuvT  = (unsigned short*)ws;  ws += 65536;
    unsigned short* woutT = (unsigned short*)ws;  ws += 262144;
    unsigned short* wukb  = (unsigned short*)ws;  ws += 65536;
    float* part  = ws;        ws += 2621440;   // 4 qI slabs + 8 kI slabs

    // ---- 1. selection-path GEMMs (fp32): qI KS=4, kI KS=8 -> 2560 blocks
    {
        MGK m{};
        float* qIP = part;                 // 4 x 524288
        float* kIP = part + 2097152;       // 8 x 65536
        m.A[0]=x; m.lda[0]=1024; m.K[0]=1024;
        m.A[1]=x; m.lda[1]=1024; m.K[1]=1024;
        m.B[0]=w_q_idx; m.Cw[0]=qIP; m.ldb[0]=512; m.wldc[0]=512; m.N[0]=512; m.KS[0]=4; m.ntiles[0]=8; m.pstride[0]=524288;
        m.B[1]=w_k_idx; m.Cw[1]=kIP; m.ldb[1]=64;  m.wldc[1]=64;  m.N[1]=64;  m.KS[1]=8; m.ntiles[1]=1; m.pstride[1]=65536;
        m.ustart[0]=0; m.ustart[1]=32; m.ustart[2]=40;
        m.ne = 2;
        gemmk<<<dim3(40, 64), dim3(128), 0, stream>>>(m);
    }

    // ---- 2. weight transpose+cast to bf16 [N][K]
    {
        TC8 tc{};
        tc.src[0]=w_dkv; tc.dst[0]=wdkvT; tc.N[0]=256;  tc.Kld[0]=1024; tc.Ntiles[0]=4;
        tc.src[1]=w_dq;  tc.dst[1]=wdqT;  tc.N[1]=512;  tc.Kld[1]=1024; tc.Ntiles[1]=8;
        tc.src[2]=w_kr;  tc.dst[2]=wkrT;  tc.N[2]=32;   tc.Kld[2]=1024; tc.Ntiles[2]=1;
        tc.src[3]=w_uq;  tc.dst[3]=wuqT;  tc.N[3]=512;  tc.Kld[3]=512;  tc.Ntiles[3]=8;
        tc.src[4]=w_qr;  tc.dst[4]=wqrT;  tc.N[4]=256;  tc.Kld[4]=512;  tc.Ntiles[4]=4;
        tc.src[5]=w_uv;  tc.dst[5]=wuvT;  tc.N[5]=512;  tc.Kld[5]=256;  tc.Ntiles[5]=8;
        tc.src[6]=w_out; tc.dst[6]=woutT; tc.N[6]=1024; tc.Kld[6]=512;  tc.Ntiles[6]=16;
        int bs[8] = {0, 64, 192, 208, 272, 304, 336, 464};
        for (int i = 0; i < 8; ++i) tc.bstart[i] = bs[i];
        tc.ne = 7;
        tcast<<<dim3(464), dim3(256), 0, stream>>>(tc);
    }

    // ---- 3. stage-1 value projections (bf16 MFMA): ckv, cq, xkr
    {
        MFG m{};
        for (int i = 0; i < 3; ++i) { m.A[i]=x; m.lda[i]=1024; m.K[i]=1024; }
        m.B[0]=wdkvT; m.C[0]=ckv; m.ldb[0]=1024; m.ldc[0]=256; m.N[0]=256;
        m.B[1]=wdqT;  m.C[1]=cq;  m.ldb[1]=1024; m.ldc[1]=512; m.N[1]=512;
        m.B[2]=wkrT;  m.C[2]=xkr; m.ldb[2]=1024; m.ldc[2]=32;  m.N[2]=32;
        m.tstart[0]=0; m.tstart[1]=4; m.tstart[2]=12; m.tstart[3]=13;
        m.ne = 3;
        mgemm<<<dim3(13, 16), dim3(256), 0, stream>>>(m);
    }

    // ---- 4. small prep
    prep_small<<<dim3(648), dim3(256), 0, stream>>>(xkr, raw_delta, w_uk, mu, cscb, cssb, wukb);

    // ---- 5. stage-2: qc, qrp (bf16 MFMA)
    {
        MFG m{};
        for (int i = 0; i < 2; ++i) { m.A[i]=cq; m.lda[i]=512; m.K[i]=512; }
        m.B[0]=wuqT; m.C[0]=qc;  m.ldb[0]=512; m.ldc[0]=512; m.N[0]=512;
        m.B[1]=wqrT; m.C[1]=qrp; m.ldb[1]=512; m.ldc[1]=256; m.N[1]=256;
        m.tstart[0]=0; m.tstart[1]=8; m.tstart[2]=12;
        m.ne = 2;
        mgemm<<<dim3(12, 16), dim3(256), 0, stream>>>(m);
    }

    pope_q_kernel<<<dim3(1024), dim3(128), 0, stream>>>(qrp, raw_delta, qrr);

    // ---- 6. qabs (bf16 MFMA, 8 head entries)
    {
        MFG m{};
        for (int h = 0; h < 8; ++h) {
            m.A[h] = qc + h * 64;   m.lda[h] = 512;  m.K[h] = 64;
            m.B[h] = wukb + h * 64; m.ldb[h] = 512;
            m.C[h] = qabs + h * 256; m.ldc[h] = 2048; m.N[h] = 256;
            m.tstart[h] = h * 4;
        }
        m.tstart[8] = 32;
        m.ne = 8;
        mgemm<<<dim3(32, 16), dim3(256), 0, stream>>>(m);
    }

    // ---- 7. indexer (fused 4/8-slab reduce) + exact top-k
    indexer_kernel<<<dim3(16, 32), dim3(256), 0, stream>>>(part, part + 2097152, w_idx, Ibuf);
    topk_kernel<<<dim3(256), dim3(256), 0, stream>>>(Ibuf, idxb);

    // ---- 8. fused attention v5 -> olat
    attn_kernel<<<dim3(1024), dim3(256), 0, stream>>>(qabs, qrr, ckv, mu, cscb, cssb, idxb, olat);

    // ---- 9. stage-3: outh_h = olat_h @ w_uv_h (bf16 MFMA)
    {
        MFG m{};
        for (int h = 0; h < 8; ++h) {
            m.A[h] = olat + h * 256;      m.lda[h] = 2048; m.K[h] = 256;
            m.B[h] = wuvT + h * 64 * 256; m.ldb[h] = 256;
            m.C[h] = outh + h * 64;       m.ldc[h] = 512;  m.N[h] = 64;
            m.tstart[h] = h;
        }
        m.tstart[8] = 8;
        m.ne = 8;
        mgemm<<<dim3(8, 16), dim3(256), 0, stream>>>(m);
    }

    // ---- 10. stage-4: out = outh @ w_out (bf16 MFMA)
    {
        MFG m{};
        m.A[0] = outh;  m.lda[0] = 512; m.K[0] = 512;
        m.B[0] = woutT; m.ldb[0] = 512;
        m.C[0] = out;   m.ldc[0] = 1024; m.N[0] = 1024;
        m.tstart[0] = 0; m.tstart[1] = 16;
        m.ne = 1;
        mgemm<<<dim3(16, 16), dim3(256), 0, stream>>>(m);
    }
}

// Round 9
// 231.926 us; speedup vs baseline: 1.0635x; 1.0635x over previous
//
#include <hip/hip_runtime.h>
#include <math.h>

#define S_LEN 1024
#define NH 8

typedef __attribute__((ext_vector_type(8))) short bf16x8;
typedef __attribute__((ext_vector_type(4))) float f32x4;

__device__ __forceinline__ float sp_softplus(float x) {
    return fmaxf(x, 0.f) + log1pf(expf(-fabsf(x)));
}

__device__ __forceinline__ unsigned short bfu(float f) {
    unsigned u = __float_as_uint(f);
    unsigned r = (u + 0x7FFFu + ((u >> 16) & 1u)) >> 16;   // RNE
    return (unsigned short)r;
}

// ============ FRONT mega-kernel: sel-GEMM + weight tcast + cs + wukb =========
// blocks [0,1152): fp32 sel GEMM, two 128-thr halves per block.
//   unit u = 2*(bx%18) + half; u<32: qI (KS=4), u in [32,36): kI (KS=4).
//   qI per-output fmac chain identical to r8 (Klocal=256, k-ascending).
// blocks [1152,1616): tcast (7 weight transposes to bf16 [N][K])
// blocks [1616,1624): key-PoPE cos/sin table
// blocks [1624,2136): w_uk cast
struct FRONT {
    const float *x, *wqidx, *wkidx, *raw_delta, *wuk;
    const float *wdkv, *wdq, *wkr, *wuq, *wqr, *wuv, *wout;
    float *qIP, *kIP, *csc, *css;
    unsigned short *wdkvT, *wdqT, *wkrT, *wuqT, *wqrT, *wuvT, *woutT, *wukb;
};

__global__ __launch_bounds__(256) void front_kernel(FRONT f)
{
    __shared__ float As[2][16][18];
    __shared__ float Bs[2][16][68];
    __shared__ unsigned short tile[64][65];
    int bx = blockIdx.x;
    if (bx < 1152) {
        int gx = bx % 18, gy = bx / 18;
        int half = threadIdx.x >> 7;
        int t = threadIdx.x & 127;
        int u = gx * 2 + half;
        const float* B; float* C;
        int ldb, N, n0, kb;
        if (u < 32) {
            B = f.wqidx; ldb = 512; N = 512;
            C = f.qIP + (long)(u >> 3) * 524288;
            n0 = (u & 7) * 64;
            kb = (u >> 3) * 256;
        } else {
            B = f.wkidx; ldb = 64; N = 64;
            C = f.kIP + (long)(u - 32) * 65536;
            n0 = 0;
            kb = (u - 32) * 256;
        }
        int ke = kb + 256;
        int m0 = gy * 16;
        int ar = t >> 2, ak = t & 3;
        int bk = t >> 3, bn = t & 7;
        int ty = t >> 4, tx = t & 15;

        float4 aN = make_float4(0.f, 0.f, 0.f, 0.f);
        if (t < 64) aN = *(const float4*)(f.x + (long)(m0 + ar) * 1024 + kb + ak * 4);
        float4 b0 = *(const float4*)(B + (long)(kb + bk) * ldb + n0 + bn * 4);
        float4 b1 = *(const float4*)(B + (long)(kb + bk) * ldb + n0 + (bn + 8) * 4);
        float acc[2][4] = {};
        for (int k0 = kb; k0 < ke; k0 += 16) {
            if (t < 64) {
                As[half][ak * 4 + 0][ar] = aN.x;
                As[half][ak * 4 + 1][ar] = aN.y;
                As[half][ak * 4 + 2][ar] = aN.z;
                As[half][ak * 4 + 3][ar] = aN.w;
            }
            *(float4*)&Bs[half][bk][bn * 4] = b0;
            *(float4*)&Bs[half][bk][(bn + 8) * 4] = b1;
            __syncthreads();
            if (k0 + 16 < ke) {
                if (t < 64) aN = *(const float4*)(f.x + (long)(m0 + ar) * 1024 + (k0 + 16) + ak * 4);
                b0 = *(const float4*)(B + (long)(k0 + 16 + bk) * ldb + n0 + bn * 4);
                b1 = *(const float4*)(B + (long)(k0 + 16 + bk) * ldb + n0 + (bn + 8) * 4);
            }
            #pragma unroll
            for (int kk = 0; kk < 16; ++kk) {
                float2 a = *(float2*)&As[half][kk][ty * 2];
                float4 b = *(float4*)&Bs[half][kk][tx * 4];
                acc[0][0] += a.x * b.x; acc[0][1] += a.x * b.y;
                acc[0][2] += a.x * b.z; acc[0][3] += a.x * b.w;
                acc[1][0] += a.y * b.x; acc[1][1] += a.y * b.y;
                acc[1][2] += a.y * b.z; acc[1][3] += a.y * b.w;
            }
            __syncthreads();
        }
        #pragma unroll
        for (int i = 0; i < 2; ++i) {
            float4 v = make_float4(acc[i][0], acc[i][1], acc[i][2], acc[i][3]);
            *(float4*)(C + (long)(m0 + ty * 2 + i) * N + n0 + tx * 4) = v;
        }
    } else if (bx < 1616) {
        int b = bx - 1152;
        const float* srcs[7] = {f.wdkv, f.wdq, f.wkr, f.wuq, f.wqr, f.wuv, f.wout};
        unsigned short* dsts[7] = {f.wdkvT, f.wdqT, f.wkrT, f.wuqT, f.wqrT, f.wuvT, f.woutT};
        const int Ns[7]   = {256, 512, 32, 512, 256, 512, 1024};
        const int Klds[7] = {1024, 1024, 1024, 512, 512, 256, 512};
        const int Ntl[7]  = {4, 8, 1, 8, 4, 8, 16};
        const int bst[8]  = {0, 64, 192, 208, 272, 304, 336, 464};
        int e = 0;
        #pragma unroll
        for (int i = 1; i < 7; ++i) if (b >= bst[i]) e = i;
        int lb = b - bst[e];
        int nt = lb % Ntl[e], kt = lb / Ntl[e];
        const float* src = srcs[e];
        unsigned short* dst = dsts[e];
        int N = Ns[e], Kld = Klds[e];
        int k0 = kt * 64, n0 = nt * 64;
        int t = threadIdx.x;
        int c = t & 63, r4 = t >> 6;
        #pragma unroll
        for (int it = 0; it < 16; ++it) {
            int r = it * 4 + r4;
            float v = (n0 + c < N) ? src[(long)(k0 + r) * N + n0 + c] : 0.f;
            tile[r][c] = bfu(v);
        }
        __syncthreads();
        int wq = t & 7;
        #pragma unroll
        for (int itw = 0; itw < 2; ++itw) {
            int wr = itw * 32 + (t >> 3);
            if (n0 + wr < N) {
                unsigned short v[8];
                #pragma unroll
                for (int j = 0; j < 8; ++j) v[j] = tile[wq * 8 + j][wr];
                *(uint4*)(dst + (long)(n0 + wr) * Kld + k0 + wq * 8) = *(uint4*)v;
            }
        }
    } else if (bx < 1624) {
        int idx = (bx - 1616) * 256 + threadIdx.x;     // 0..2047
        int j = idx >> 4, i = idx & 15;
        float rd = f.raw_delta[i];
        float delta = -6.283185307179586f * (1.f / (1.f + expf(-rd)));
        float th = exp2f(-(float)i * 0.83048202372184f);
        float ang = (float)j * th + delta;
        float sv, cv;
        sincosf(ang, &sv, &cv);
        f.csc[idx] = cv;
        f.css[idx] = sv;
    } else {
        int idx = (bx - 1624) * 256 + threadIdx.x;     // 0..131071
        f.wukb[idx] = bfu(f.wuk[idx]);
    }
}

// ============ bf16 MFMA routed multi-GEMM (VALUE PATH) =======================
struct MFG {
    const float* A[10]; const unsigned short* B[10]; float* C[10];
    int lda[10], ldb[10], ldc[10], K[10], N[10];
    int tstart[11]; int ne;
};

__global__ __launch_bounds__(256) void mgemm(MFG mg)
{
    int bx = blockIdx.x, e = 0;
    #pragma unroll
    for (int i = 1; i < 10; ++i) if (i < mg.ne && bx >= mg.tstart[i]) e = i;
    const float* A = mg.A[e];
    const unsigned short* B = mg.B[e];
    float* C = mg.C[e];
    int lda = mg.lda[e], ldb = mg.ldb[e], ldc = mg.ldc[e];
    int K = mg.K[e], N = mg.N[e];
    int m0 = blockIdx.y * 64, n0 = (bx - mg.tstart[e]) * 64;

    __shared__ unsigned short As[64][40];
    __shared__ unsigned short Bs[64][40];
    int t = threadIdx.x;
    int srow = t >> 2, skq = t & 3;
    int wid = t >> 6, l = t & 63;
    int wm = (wid >> 1) * 32, wn = (wid & 1) * 32;
    int fr = l & 15, fk = (l >> 4) * 8;
    bool bok = (n0 + srow) < N;

    f32x4 acc00 = {0.f, 0.f, 0.f, 0.f};
    f32x4 acc01 = {0.f, 0.f, 0.f, 0.f};
    f32x4 acc10 = {0.f, 0.f, 0.f, 0.f};
    f32x4 acc11 = {0.f, 0.f, 0.f, 0.f};

    for (int k0 = 0; k0 < K; k0 += 32) {
        {
            const float* ap = A + (long)(m0 + srow) * lda + k0 + skq * 8;
            float4 v0 = *(const float4*)ap;
            float4 v1 = *(const float4*)(ap + 4);
            unsigned short* d = &As[srow][skq * 8];
            d[0] = bfu(v0.x); d[1] = bfu(v0.y); d[2] = bfu(v0.z); d[3] = bfu(v0.w);
            d[4] = bfu(v1.x); d[5] = bfu(v1.y); d[6] = bfu(v1.z); d[7] = bfu(v1.w);
        }
        {
            uint4 bv = make_uint4(0u, 0u, 0u, 0u);
            if (bok) bv = *(const uint4*)(B + (long)(n0 + srow) * ldb + k0 + skq * 8);
            *(uint4*)&Bs[srow][skq * 8] = bv;
        }
        __syncthreads();
        bf16x8 a0 = *(bf16x8*)&As[wm + fr][fk];
        bf16x8 a1 = *(bf16x8*)&As[wm + 16 + fr][fk];
        bf16x8 b0 = *(bf16x8*)&Bs[wn + fr][fk];
        bf16x8 b1 = *(bf16x8*)&Bs[wn + 16 + fr][fk];
        acc00 = __builtin_amdgcn_mfma_f32_16x16x32_bf16(a0, b0, acc00, 0, 0, 0);
        acc01 = __builtin_amdgcn_mfma_f32_16x16x32_bf16(a0, b1, acc01, 0, 0, 0);
        acc10 = __builtin_amdgcn_mfma_f32_16x16x32_bf16(a1, b0, acc10, 0, 0, 0);
        acc11 = __builtin_amdgcn_mfma_f32_16x16x32_bf16(a1, b1, acc11, 0, 0, 0);
        __syncthreads();
    }
    int crow = (l >> 4) * 4;
    int col0 = n0 + wn + fr, col1 = n0 + wn + 16 + fr;
    if (col0 < N) {
        #pragma unroll
        for (int r = 0; r < 4; ++r) {
            C[(long)(m0 + wm + crow + r) * ldc + col0]      = acc00[r];
            C[(long)(m0 + wm + 16 + crow + r) * ldc + col0] = acc10[r];
        }
    }
    if (col1 < N) {
        #pragma unroll
        for (int r = 0; r < 4; ++r) {
            C[(long)(m0 + wm + crow + r) * ldc + col1]      = acc01[r];
            C[(long)(m0 + wm + 16 + crow + r) * ldc + col1] = acc11[r];
        }
    }
}

// ---------------- PoPE for queries + mu (fused) -------------------------------
__global__ __launch_bounds__(128) void pope_mu_kernel(
    const float* __restrict__ pre, const float* __restrict__ raw_delta,
    float* __restrict__ outq, const float* __restrict__ xkr,
    float* __restrict__ mu)
{
    int b = blockIdx.x, tid = threadIdx.x;
    if (b < 1024) {
        int t = b;
        int h = tid >> 4, i = tid & 15;
        float rd = raw_delta[i];
        float delta = -6.283185307179586f * (1.f / (1.f + expf(-rd)));
        float th = exp2f(-(float)i * 0.83048202372184f);
        float ang = (float)t * th + delta;
        float sv, cv;
        sincosf(ang, &sv, &cv);
        float m1 = sp_softplus(pre[t * 256 + h * 32 + i]);
        float m2 = sp_softplus(pre[t * 256 + h * 32 + 16 + i]);
        outq[t * 256 + h * 32 + i]      = m1 * cv - m2 * sv;
        outq[t * 256 + h * 32 + 16 + i] = m1 * sv + m2 * cv;
    } else {
        int i = (b - 1024) * 128 + tid;
        mu[i] = sp_softplus(xkr[i]);
    }
}

// -------- lightning indexer w/ fused split-K reduce (4 qI slabs, 4 kI slabs) --
__global__ __launch_bounds__(256) void indexer_kernel(
    const float* __restrict__ qIP, const float* __restrict__ kIP,
    const float* __restrict__ w_idx, float* __restrict__ I)
{
    int sb = blockIdx.x, tb = blockIdx.y;
    if (sb * 64 > tb * 32 + 31) return;
    int t0 = tb * 32, s0 = sb * 64;
    __shared__ float ksT[64][68];
    __shared__ float qs[32][68];
    int t = threadIdx.x;
    {
        int r = t & 63, q = t >> 6;
        #pragma unroll
        for (int u = 0; u < 4; ++u) {
            int c4 = q * 4 + u;
            long off = (long)(s0 + r) * 64 + c4 * 4;
            float4 v = *(const float4*)(kIP + off);
            #pragma unroll
            for (int s = 1; s < 4; ++s) {
                float4 v2 = *(const float4*)(kIP + (long)s * 65536 + off);
                v.x += v2.x; v.y += v2.y; v.z += v2.z; v.w += v2.w;
            }
            ksT[c4 * 4 + 0][r] = v.x;
            ksT[c4 * 4 + 1][r] = v.y;
            ksT[c4 * 4 + 2][r] = v.z;
            ksT[c4 * 4 + 3][r] = v.w;
        }
    }
    int ty = t >> 4, tx = t & 15;
    float accI[2][4] = {};
    for (int h = 0; h < 8; ++h) {
        __syncthreads();
        {
            int r = t >> 3, q = t & 7;
            long base = (long)(t0 + r) * 512 + h * 64;
            #pragma unroll
            for (int half = 0; half < 2; ++half) {
                long off = base + (q + half * 8) * 4;
                float4 a = *(const float4*)(qIP + off);
                #pragma unroll
                for (int s = 1; s < 4; ++s) {
                    float4 a1 = *(const float4*)(qIP + (long)s * 524288 + off);
                    a.x += a1.x; a.y += a1.y; a.z += a1.z; a.w += a1.w;
                }
                *(float4*)&qs[r][(q + half * 8) * 4] = a;
            }
        }
        __syncthreads();
        float acc[2][4] = {};
        #pragma unroll
        for (int dc = 0; dc < 4; ++dc) {
            float a0[16], a1[16];
            #pragma unroll
            for (int u = 0; u < 4; ++u) {
                float4 v0 = *(float4*)&qs[ty * 2][dc * 16 + u * 4];
                float4 v1 = *(float4*)&qs[ty * 2 + 1][dc * 16 + u * 4];
                a0[u * 4 + 0] = v0.x; a0[u * 4 + 1] = v0.y; a0[u * 4 + 2] = v0.z; a0[u * 4 + 3] = v0.w;
                a1[u * 4 + 0] = v1.x; a1[u * 4 + 1] = v1.y; a1[u * 4 + 2] = v1.z; a1[u * 4 + 3] = v1.w;
            }
            #pragma unroll
            for (int kk = 0; kk < 16; ++kk) {
                int d = dc * 16 + kk;
                float4 b = *(float4*)&ksT[d][tx * 4];
                acc[0][0] += a0[kk] * b.x; acc[0][1] += a0[kk] * b.y;
                acc[0][2] += a0[kk] * b.z; acc[0][3] += a0[kk] * b.w;
                acc[1][0] += a1[kk] * b.x; acc[1][1] += a1[kk] * b.y;
                acc[1][2] += a1[kk] * b.z; acc[1][3] += a1[kk] * b.w;
            }
        }
        float wh = w_idx[h];
        #pragma unroll
        for (int i = 0; i < 2; ++i)
            #pragma unroll
            for (int j = 0; j < 4; ++j)
                accI[i][j] += wh * fmaxf(acc[i][j], 0.f);
    }
    #pragma unroll
    for (int i = 0; i < 2; ++i) {
        float4 v = make_float4(accI[i][0], accI[i][1], accI[i][2], accI[i][3]);
        *(float4*)&I[(long)(t0 + ty * 2 + i) * 1024 + s0 + tx * 4] = v;
    }
}

// -------- exact top-k (unchanged) ---------------------------------------------
__global__ __launch_bounds__(256) void topk_kernel(
    const float* __restrict__ I, int* __restrict__ idxout)
{
    int t = blockIdx.x * 4 + (threadIdx.x >> 6);
    int lane = threadIdx.x & 63;
    int smin = max(0, t - 63);
    int w = min(64, t + 1);
    if (lane < w) idxout[t * 128 + lane] = smin + lane;
    for (int q = t + 1 + lane; q < 128; q += 64)
        idxout[t * 128 + q] = q;
    int f = max(0, t - 63);
    int m = min(f, 64);
    if (m == 0) return;
    const float* row = I + (long)t * 1024;
    unsigned long long key[16];
    #pragma unroll
    for (int i = 0; i < 16; ++i) {
        int s = i * 64 + lane;
        key[i] = 0ull;
        if (s < f) {
            unsigned u = __float_as_uint(row[s]);
            unsigned ou = (u & 0x80000000u) ? ~u : (u | 0x80000000u);
            key[i] = ((unsigned long long)ou << 32) | (0xFFFFFFFFu - (unsigned)s);
        }
    }
    for (int it = 0; it < m; ++it) {
        unsigned long long best = key[0];
        #pragma unroll
        for (int i = 1; i < 16; ++i) best = key[i] > best ? key[i] : best;
        #pragma unroll
        for (int off = 32; off > 0; off >>= 1) {
            unsigned long long o = __shfl_xor(best, off, 64);
            best = o > best ? o : best;
        }
        int s = (int)(0xFFFFFFFFu - (unsigned)(best & 0xFFFFFFFFull));
        if (lane == 0) idxout[t * 128 + w + it] = s;
        if ((s & 63) == lane) {
            int slot = s >> 6;
            #pragma unroll
            for (int i = 0; i < 16; ++i)
                if (i == slot) key[i] = 0ull;
        }
    }
}

// -------- fused attention v6: v5 + Qb aliased into kv -> 40.6 KB, 4 blocks/CU -
__global__ __launch_bounds__(256) void attn_kernel(
    const float* __restrict__ qabs, const float* __restrict__ qrr,
    const float* __restrict__ ckv, const float* __restrict__ mu,
    const float* __restrict__ csc, const float* __restrict__ css,
    const int* __restrict__ idxb, float* __restrict__ olat)
{
    __shared__ unsigned short kv[64][296];   // chunks: cols 0..255 ckv, 256..287 kr
    __shared__ float sc[8][68];
    __shared__ int idx_s[128];

    int t = blockIdx.x, tid = threadIdx.x;
    int w = tid >> 6, l = tid & 63;
    const float scale = 0.10206207261596575f;

    if (tid < 128) idx_s[tid] = idxb[t * 128 + tid];
    {   // stage Q into kv rows 0..15 (aliased; consumed into qf before staging)
        int r = tid >> 5;
        for (int c = tid & 31; c < 296; c += 32) {
            float v = 0.f;
            if (c < 256)      v = qabs[(long)t * 2048 + r * 256 + c] * scale;
            else if (c < 288) v = qrr[(long)t * 256 + r * 32 + (c - 256)] * scale;
            kv[r][c] = bfu(v);
            kv[r + 8][c] = 0;
        }
    }
    __syncthreads();

    // hoist Q B-frags to regs (constant across chunks)
    bf16x8 qf[9];
    #pragma unroll
    for (int ks = 0; ks < 9; ++ks)
        qf[ks] = *(bf16x8*)&kv[l & 15][ks * 32 + (l >> 4) * 8];

    float mrun0 = -INFINITY, mrun1 = -INFINITY;
    float lrun0 = 0.f, lrun1 = 0.f;
    float acc0 = 0, acc1 = 0, acc2 = 0, acc3 = 0;
    float acc4 = 0, acc5 = 0, acc6 = 0, acc7 = 0;

    int sr = tid >> 2, sq = tid & 3;
    int hme = 2 * w + (l >> 5);
    int c8 = (l & 31) * 8;

    #pragma unroll
    for (int chunk = 0; chunk < 2; ++chunk) {
        __syncthreads();   // prev phase done reading kv (incl. qf loads)
        {   // stage ckv rows -> bf16
            int src = idx_s[chunk * 64 + sr];
            const float4* sp4 = (const float4*)(ckv + (long)src * 256) + sq * 16;
            #pragma unroll
            for (int g = 0; g < 8; ++g) {
                float4 v0 = sp4[g * 2];
                float4 v1 = sp4[g * 2 + 1];
                unsigned short hh[8];
                hh[0] = bfu(v0.x); hh[1] = bfu(v0.y); hh[2] = bfu(v0.z); hh[3] = bfu(v0.w);
                hh[4] = bfu(v1.x); hh[5] = bfu(v1.y); hh[6] = bfu(v1.z); hh[7] = bfu(v1.w);
                *(uint4*)&kv[sr][sq * 64 + g * 8] = *(uint4*)hh;
            }
        }
        {   // stage kr cols (PoPE at pos = global slot)
            int src = idx_s[chunk * 64 + sr];
            int j = chunk * 64 + sr;
            unsigned short hh[8];
            #pragma unroll
            for (int ii = 0; ii < 8; ++ii) {
                int i = sq * 8 + ii;
                int i15 = i & 15;
                float m1 = mu[src * 32 + i15];
                float m2 = mu[src * 32 + 16 + i15];
                float cv = csc[j * 16 + i15];
                float sv = css[j * 16 + i15];
                float kr = (i < 16) ? (m1 * cv - m2 * sv) : (m1 * sv + m2 * cv);
                hh[ii] = bfu(kr);
            }
            *(uint4*)&kv[sr][256 + sq * 8] = *(uint4*)hh;
        }
        __syncthreads();

        // QK^T via MFMA: wave w -> slot tile w*16..w*16+15
        f32x4 st = {0.f, 0.f, 0.f, 0.f};
        #pragma unroll
        for (int ks = 0; ks < 9; ++ks) {
            bf16x8 af = *(bf16x8*)&kv[w * 16 + (l & 15)][ks * 32 + (l >> 4) * 8];
            st = __builtin_amdgcn_mfma_f32_16x16x32_bf16(af, qf[ks], st, 0, 0, 0);
        }
        {   // scatter S^T to sc[h][slot] (h<8 only)
            int hcol = l & 15;
            int srow = w * 16 + (l >> 4) * 4;
            if (hcol < 8) {
                #pragma unroll
                for (int r = 0; r < 4; ++r) sc[hcol][srow + r] = st[r];
            }
        }
        __syncthreads();

        // online softmax: wave w handles heads 2w, 2w+1
        float rh0, rh1;
        {
            int h = 2 * w;
            float v = sc[h][l];
            float mx = v;
            #pragma unroll
            for (int off = 32; off > 0; off >>= 1) mx = fmaxf(mx, __shfl_xor(mx, off));
            float mnew = fmaxf(mrun0, mx);
            float p = expf(v - mnew);
            float ps = p;
            #pragma unroll
            for (int off = 32; off > 0; off >>= 1) ps += __shfl_xor(ps, off);
            rh0 = expf(mrun0 - mnew);
            lrun0 = lrun0 * rh0 + ps;
            mrun0 = mnew;
            sc[h][l] = p;
        }
        {
            int h = 2 * w + 1;
            float v = sc[h][l];
            float mx = v;
            #pragma unroll
            for (int off = 32; off > 0; off >>= 1) mx = fmaxf(mx, __shfl_xor(mx, off));
            float mnew = fmaxf(mrun1, mx);
            float p = expf(v - mnew);
            float ps = p;
            #pragma unroll
            for (int off = 32; off > 0; off >>= 1) ps += __shfl_xor(ps, off);
            rh1 = expf(mrun1 - mnew);
            lrun1 = lrun1 * rh1 + ps;
            mrun1 = mnew;
            sc[h][l] = p;
        }
        float rsel = (l >> 5) ? rh1 : rh0;
        acc0 *= rsel; acc1 *= rsel; acc2 *= rsel; acc3 *= rsel;
        acc4 *= rsel; acc5 *= rsel; acc6 *= rsel; acc7 *= rsel;

        // PV (VALU): lane owns head hme, c-octet c8
        #pragma unroll 4
        for (int j = 0; j < 64; ++j) {
            float p = sc[hme][j];
            uint4 vv = *(uint4*)&kv[j][c8];
            acc0 += p * __uint_as_float(vv.x << 16);
            acc1 += p * __uint_as_float(vv.x & 0xffff0000u);
            acc2 += p * __uint_as_float(vv.y << 16);
            acc3 += p * __uint_as_float(vv.y & 0xffff0000u);
            acc4 += p * __uint_as_float(vv.z << 16);
            acc5 += p * __uint_as_float(vv.z & 0xffff0000u);
            acc6 += p * __uint_as_float(vv.w << 16);
            acc7 += p * __uint_as_float(vv.w & 0xffff0000u);
        }
    }

    float lr = (l >> 5) ? lrun1 : lrun0;
    float inv = 1.f / lr;
    float* op = olat + (long)t * 2048 + hme * 256 + c8;
    *(float4*)op       = make_float4(acc0 * inv, acc1 * inv, acc2 * inv, acc3 * inv);
    *(float4*)(op + 4) = make_float4(acc4 * inv, acc5 * inv, acc6 * inv, acc7 * inv);
}

extern "C" void kernel_launch(void* const* d_in, const int* in_sizes, int n_in,
                              void* d_out, int out_size, void* d_ws, size_t ws_size,
                              hipStream_t stream)
{
    const float* x         = (const float*)d_in[0];
    const float* w_q_idx   = (const float*)d_in[1];
    const float* w_k_idx   = (const float*)d_in[2];
    const float* w_idx     = (const float*)d_in[3];
    const float* raw_delta = (const float*)d_in[4];
    const float* w_dkv     = (const float*)d_in[5];
    const float* w_uk      = (const float*)d_in[6];
    const float* w_uv      = (const float*)d_in[7];
    const float* w_dq      = (const float*)d_in[8];
    const float* w_uq      = (const float*)d_in[9];
    const float* w_qr      = (const float*)d_in[10];
    const float* w_kr      = (const float*)d_in[11];
    const float* w_out     = (const float*)d_in[12];
    (void)in_sizes; (void)n_in; (void)out_size; (void)ws_size;
    float* out = (float*)d_out;

    float* ws = (float*)d_ws;
    float* ckv   = ws;        ws += 1024 * 256;
    float* cq    = ws;        ws += 1024 * 512;
    float* xkr   = ws;        ws += 1024 * 32;
    float* qrp   = ws;        ws += 1024 * 256;
    float* qrr   = ws;        ws += 1024 * 256;
    float* qc    = ws;        ws += 1024 * 512;
    float* qabs  = ws;        ws += 1024 * 2048;
    float* Ibuf  = ws;        ws += 1024 * 1024;
    int*   idxb  = (int*)ws;  ws += 1024 * 128;
    float* olat  = ws;        ws += 1024 * 2048;
    float* outh  = ws;        ws += 1024 * 512;
    float* mu    = ws;        ws += 1024 * 32;
    float* cscb  = ws;        ws += 128 * 16;
    float* cssb  = ws;        ws += 128 * 16;
    unsigned short* wdkvT = (unsigned short*)ws;  ws += 131072;
    unsigned short* wdqT  = (unsigned short*)ws;  ws += 262144;
    unsigned short* wkrT  = (unsigned short*)ws;  ws += 16384;
    unsigned short* wuqT  = (unsigned short*)ws;  ws += 131072;
    unsigned short* wqrT  = (unsigned short*)ws;  ws += 65536;
    unsigned short* wuvT  = (unsigned short*)ws;  ws += 65536;
    unsigned short* woutT = (unsigned short*)ws;  ws += 262144;
    unsigned short* wukb  = (unsigned short*)ws;  ws += 65536;
    float* part  = ws;        ws += 2359296;   // 4 qI slabs + 4 kI slabs
    float* qIP = part;                  // 4 x 524288
    float* kIP = part + 2097152;        // 4 x 65536

    // ---- L1: FRONT mega-launch (sel GEMM + weight tcast + cs + wukb)
    {
        FRONT f{};
        f.x = x; f.wqidx = w_q_idx; f.wkidx = w_k_idx; f.raw_delta = raw_delta; f.wuk = w_uk;
        f.wdkv = w_dkv; f.wdq = w_dq; f.wkr = w_kr; f.wuq = w_uq; f.wqr = w_qr;
        f.wuv = w_uv; f.wout = w_out;
        f.qIP = qIP; f.kIP = kIP; f.csc = cscb; f.css = cssb;
        f.wdkvT = wdkvT; f.wdqT = wdqT; f.wkrT = wkrT; f.wuqT = wuqT;
        f.wqrT = wqrT; f.wuvT = wuvT; f.woutT = woutT; f.wukb = wukb;
        front_kernel<<<dim3(2136), dim3(256), 0, stream>>>(f);
    }

    // ---- L2: stage-1 value projections (bf16 MFMA): ckv, cq, xkr
    {
        MFG m{};
        for (int i = 0; i < 3; ++i) { m.A[i]=x; m.lda[i]=1024; m.K[i]=1024; }
        m.B[0]=wdkvT; m.C[0]=ckv; m.ldb[0]=1024; m.ldc[0]=256; m.N[0]=256;
        m.B[1]=wdqT;  m.C[1]=cq;  m.ldb[1]=1024; m.ldc[1]=512; m.N[1]=512;
        m.B[2]=wkrT;  m.C[2]=xkr; m.ldb[2]=1024; m.ldc[2]=32;  m.N[2]=32;
        m.tstart[0]=0; m.tstart[1]=4; m.tstart[2]=12; m.tstart[3]=13;
        m.ne = 3;
        mgemm<<<dim3(13, 16), dim3(256), 0, stream>>>(m);
    }

    // ---- L3: stage-2: qc, qrp (bf16 MFMA)
    {
        MFG m{};
        for (int i = 0; i < 2; ++i) { m.A[i]=cq; m.lda[i]=512; m.K[i]=512; }
        m.B[0]=wuqT; m.C[0]=qc;  m.ldb[0]=512; m.ldc[0]=512; m.N[0]=512;
        m.B[1]=wqrT; m.C[1]=qrp; m.ldb[1]=512; m.ldc[1]=256; m.N[1]=256;
        m.tstart[0]=0; m.tstart[1]=8; m.tstart[2]=12;
        m.ne = 2;
        mgemm<<<dim3(12, 16), dim3(256), 0, stream>>>(m);
    }

    // ---- L4: PoPE(q) + mu (fused)
    pope_mu_kernel<<<dim3(1280), dim3(128), 0, stream>>>(qrp, raw_delta, qrr, xkr, mu);

    // ---- L5: qabs (bf16 MFMA, 8 head entries)
    {
        MFG m{};
        for (int h = 0; h < 8; ++h) {
            m.A[h] = qc + h * 64;   m.lda[h] = 512;  m.K[h] = 64;
            m.B[h] = wukb + h * 64; m.ldb[h] = 512;
            m.C[h] = qabs + h * 256; m.ldc[h] = 2048; m.N[h] = 256;
            m.tstart[h] = h * 4;
        }
        m.tstart[8] = 32;
        m.ne = 8;
        mgemm<<<dim3(32, 16), dim3(256), 0, stream>>>(m);
    }

    // ---- L6/L7: indexer (fused 4/4-slab reduce) + exact top-k
    indexer_kernel<<<dim3(16, 32), dim3(256), 0, stream>>>(qIP, kIP, w_idx, Ibuf);
    topk_kernel<<<dim3(256), dim3(256), 0, stream>>>(Ibuf, idxb);

    // ---- L8: fused attention v6 -> olat
    attn_kernel<<<dim3(1024), dim3(256), 0, stream>>>(qabs, qrr, ckv, mu, cscb, cssb, idxb, olat);

    // ---- L9: stage-3: outh_h = olat_h @ w_uv_h (bf16 MFMA)
    {
        MFG m{};
        for (int h = 0; h < 8; ++h) {
            m.A[h] = olat + h * 256;      m.lda[h] = 2048; m.K[h] = 256;
            m.B[h] = wuvT + h * 64 * 256; m.ldb[h] = 256;
            m.C[h] = outh + h * 64;       m.ldc[h] = 512;  m.N[h] = 64;
            m.tstart[h] = h;
        }
        m.tstart[8] = 8;
        m.ne = 8;
        mgemm<<<dim3(8, 16), dim3(256), 0, stream>>>(m);
    }

    // ---- L10: stage-4: out = outh @ w_out (bf16 MFMA)
    {
        MFG m{};
        m.A[0] = outh;  m.lda[0] = 512; m.K[0] = 512;
        m.B[0] = woutT; m.ldb[0] = 512;
        m.C[0] = out;   m.ldc[0] = 1024; m.N[0] = 1024;
        m.tstart[0] = 0; m.tstart[1] = 16;
        m.ne = 1;
        mgemm<<<dim3(16, 16), dim3(256), 0, stream>>>(m);
    }
}

// Round 10
// 214.880 us; speedup vs baseline: 1.1479x; 1.0793x over previous
//
#include <hip/hip_runtime.h>
#include <math.h>

#define S_LEN 1024
#define NH 8

typedef __attribute__((ext_vector_type(8))) short bf16x8;
typedef __attribute__((ext_vector_type(4))) float f32x4;

__device__ __forceinline__ float sp_softplus(float x) {
    return fmaxf(x, 0.f) + log1pf(expf(-fabsf(x)));
}

__device__ __forceinline__ unsigned short bfu(float f) {
    unsigned u = __float_as_uint(f);
    unsigned r = (u + 0x7FFFu + ((u >> 16) & 1u)) >> 16;   // RNE
    return (unsigned short)r;
}

// ============ FRONT mega-kernel: sel-GEMM + weight tcast + cs + wukb =========
// (unchanged from r9)
struct FRONT {
    const float *x, *wqidx, *wkidx, *raw_delta, *wuk;
    const float *wdkv, *wdq, *wkr, *wuq, *wqr, *wuv, *wout;
    float *qIP, *kIP, *csc, *css;
    unsigned short *wdkvT, *wdqT, *wkrT, *wuqT, *wqrT, *wuvT, *woutT, *wukb;
};

__global__ __launch_bounds__(256) void front_kernel(FRONT f)
{
    __shared__ float As[2][16][18];
    __shared__ float Bs[2][16][68];
    __shared__ unsigned short tile[64][65];
    int bx = blockIdx.x;
    if (bx < 1152) {
        int gx = bx % 18, gy = bx / 18;
        int half = threadIdx.x >> 7;
        int t = threadIdx.x & 127;
        int u = gx * 2 + half;
        const float* B; float* C;
        int ldb, N, n0, kb;
        if (u < 32) {
            B = f.wqidx; ldb = 512; N = 512;
            C = f.qIP + (long)(u >> 3) * 524288;
            n0 = (u & 7) * 64;
            kb = (u >> 3) * 256;
        } else {
            B = f.wkidx; ldb = 64; N = 64;
            C = f.kIP + (long)(u - 32) * 65536;
            n0 = 0;
            kb = (u - 32) * 256;
        }
        int ke = kb + 256;
        int m0 = gy * 16;
        int ar = t >> 2, ak = t & 3;
        int bk = t >> 3, bn = t & 7;
        int ty = t >> 4, tx = t & 15;

        float4 aN = make_float4(0.f, 0.f, 0.f, 0.f);
        if (t < 64) aN = *(const float4*)(f.x + (long)(m0 + ar) * 1024 + kb + ak * 4);
        float4 b0 = *(const float4*)(B + (long)(kb + bk) * ldb + n0 + bn * 4);
        float4 b1 = *(const float4*)(B + (long)(kb + bk) * ldb + n0 + (bn + 8) * 4);
        float acc[2][4] = {};
        for (int k0 = kb; k0 < ke; k0 += 16) {
            if (t < 64) {
                As[half][ak * 4 + 0][ar] = aN.x;
                As[half][ak * 4 + 1][ar] = aN.y;
                As[half][ak * 4 + 2][ar] = aN.z;
                As[half][ak * 4 + 3][ar] = aN.w;
            }
            *(float4*)&Bs[half][bk][bn * 4] = b0;
            *(float4*)&Bs[half][bk][(bn + 8) * 4] = b1;
            __syncthreads();
            if (k0 + 16 < ke) {
                if (t < 64) aN = *(const float4*)(f.x + (long)(m0 + ar) * 1024 + (k0 + 16) + ak * 4);
                b0 = *(const float4*)(B + (long)(k0 + 16 + bk) * ldb + n0 + bn * 4);
                b1 = *(const float4*)(B + (long)(k0 + 16 + bk) * ldb + n0 + (bn + 8) * 4);
            }
            #pragma unroll
            for (int kk = 0; kk < 16; ++kk) {
                float2 a = *(float2*)&As[half][kk][ty * 2];
                float4 b = *(float4*)&Bs[half][kk][tx * 4];
                acc[0][0] += a.x * b.x; acc[0][1] += a.x * b.y;
                acc[0][2] += a.x * b.z; acc[0][3] += a.x * b.w;
                acc[1][0] += a.y * b.x; acc[1][1] += a.y * b.y;
                acc[1][2] += a.y * b.z; acc[1][3] += a.y * b.w;
            }
            __syncthreads();
        }
        #pragma unroll
        for (int i = 0; i < 2; ++i) {
            float4 v = make_float4(acc[i][0], acc[i][1], acc[i][2], acc[i][3]);
            *(float4*)(C + (long)(m0 + ty * 2 + i) * N + n0 + tx * 4) = v;
        }
    } else if (bx < 1616) {
        int b = bx - 1152;
        const float* srcs[7] = {f.wdkv, f.wdq, f.wkr, f.wuq, f.wqr, f.wuv, f.wout};
        unsigned short* dsts[7] = {f.wdkvT, f.wdqT, f.wkrT, f.wuqT, f.wqrT, f.wuvT, f.woutT};
        const int Ns[7]   = {256, 512, 32, 512, 256, 512, 1024};
        const int Klds[7] = {1024, 1024, 1024, 512, 512, 256, 512};
        const int Ntl[7]  = {4, 8, 1, 8, 4, 8, 16};
        const int bst[8]  = {0, 64, 192, 208, 272, 304, 336, 464};
        int e = 0;
        #pragma unroll
        for (int i = 1; i < 7; ++i) if (b >= bst[i]) e = i;
        int lb = b - bst[e];
        int nt = lb % Ntl[e], kt = lb / Ntl[e];
        const float* src = srcs[e];
        unsigned short* dst = dsts[e];
        int N = Ns[e], Kld = Klds[e];
        int k0 = kt * 64, n0 = nt * 64;
        int t = threadIdx.x;
        int c = t & 63, r4 = t >> 6;
        #pragma unroll
        for (int it = 0; it < 16; ++it) {
            int r = it * 4 + r4;
            float v = (n0 + c < N) ? src[(long)(k0 + r) * N + n0 + c] : 0.f;
            tile[r][c] = bfu(v);
        }
        __syncthreads();
        int wq = t & 7;
        #pragma unroll
        for (int itw = 0; itw < 2; ++itw) {
            int wr = itw * 32 + (t >> 3);
            if (n0 + wr < N) {
                unsigned short v[8];
                #pragma unroll
                for (int j = 0; j < 8; ++j) v[j] = tile[wq * 8 + j][wr];
                *(uint4*)(dst + (long)(n0 + wr) * Kld + k0 + wq * 8) = *(uint4*)v;
            }
        }
    } else if (bx < 1624) {
        int idx = (bx - 1616) * 256 + threadIdx.x;
        int j = idx >> 4, i = idx & 15;
        float rd = f.raw_delta[i];
        float delta = -6.283185307179586f * (1.f / (1.f + expf(-rd)));
        float th = exp2f(-(float)i * 0.83048202372184f);
        float ang = (float)j * th + delta;
        float sv, cv;
        sincosf(ang, &sv, &cv);
        f.csc[idx] = cv;
        f.css[idx] = sv;
    } else {
        int idx = (bx - 1624) * 256 + threadIdx.x;
        f.wukb[idx] = bfu(f.wuk[idx]);
    }
}

// ============ bf16 MFMA routed multi-GEMM (+ per-entry bf16 output) ==========
struct MFG {
    const float* A[10]; const unsigned short* B[10]; float* C[10];
    int lda[10], ldb[10], ldc[10], K[10], N[10], obf[10];
    int tstart[11]; int ne;
};

__global__ __launch_bounds__(256) void mgemm(MFG mg)
{
    int bx = blockIdx.x, e = 0;
    #pragma unroll
    for (int i = 1; i < 10; ++i) if (i < mg.ne && bx >= mg.tstart[i]) e = i;
    const float* A = mg.A[e];
    const unsigned short* B = mg.B[e];
    float* C = mg.C[e];
    int lda = mg.lda[e], ldb = mg.ldb[e], ldc = mg.ldc[e];
    int K = mg.K[e], N = mg.N[e];
    int m0 = blockIdx.y * 64, n0 = (bx - mg.tstart[e]) * 64;

    __shared__ unsigned short As[64][40];
    __shared__ unsigned short Bs[64][40];
    int t = threadIdx.x;
    int srow = t >> 2, skq = t & 3;
    int wid = t >> 6, l = t & 63;
    int wm = (wid >> 1) * 32, wn = (wid & 1) * 32;
    int fr = l & 15, fk = (l >> 4) * 8;
    bool bok = (n0 + srow) < N;

    f32x4 acc00 = {0.f, 0.f, 0.f, 0.f};
    f32x4 acc01 = {0.f, 0.f, 0.f, 0.f};
    f32x4 acc10 = {0.f, 0.f, 0.f, 0.f};
    f32x4 acc11 = {0.f, 0.f, 0.f, 0.f};

    for (int k0 = 0; k0 < K; k0 += 32) {
        {
            const float* ap = A + (long)(m0 + srow) * lda + k0 + skq * 8;
            float4 v0 = *(const float4*)ap;
            float4 v1 = *(const float4*)(ap + 4);
            unsigned short* d = &As[srow][skq * 8];
            d[0] = bfu(v0.x); d[1] = bfu(v0.y); d[2] = bfu(v0.z); d[3] = bfu(v0.w);
            d[4] = bfu(v1.x); d[5] = bfu(v1.y); d[6] = bfu(v1.z); d[7] = bfu(v1.w);
        }
        {
            uint4 bv = make_uint4(0u, 0u, 0u, 0u);
            if (bok) bv = *(const uint4*)(B + (long)(n0 + srow) * ldb + k0 + skq * 8);
            *(uint4*)&Bs[srow][skq * 8] = bv;
        }
        __syncthreads();
        bf16x8 a0 = *(bf16x8*)&As[wm + fr][fk];
        bf16x8 a1 = *(bf16x8*)&As[wm + 16 + fr][fk];
        bf16x8 b0 = *(bf16x8*)&Bs[wn + fr][fk];
        bf16x8 b1 = *(bf16x8*)&Bs[wn + 16 + fr][fk];
        acc00 = __builtin_amdgcn_mfma_f32_16x16x32_bf16(a0, b0, acc00, 0, 0, 0);
        acc01 = __builtin_amdgcn_mfma_f32_16x16x32_bf16(a0, b1, acc01, 0, 0, 0);
        acc10 = __builtin_amdgcn_mfma_f32_16x16x32_bf16(a1, b0, acc10, 0, 0, 0);
        acc11 = __builtin_amdgcn_mfma_f32_16x16x32_bf16(a1, b1, acc11, 0, 0, 0);
        __syncthreads();
    }
    int crow = (l >> 4) * 4;
    int col0 = n0 + wn + fr, col1 = n0 + wn + 16 + fr;
    if (mg.obf[e]) {
        unsigned short* Cu = (unsigned short*)C;
        if (col0 < N) {
            #pragma unroll
            for (int r = 0; r < 4; ++r) {
                Cu[(long)(m0 + wm + crow + r) * ldc + col0]      = bfu(acc00[r]);
                Cu[(long)(m0 + wm + 16 + crow + r) * ldc + col0] = bfu(acc10[r]);
            }
        }
        if (col1 < N) {
            #pragma unroll
            for (int r = 0; r < 4; ++r) {
                Cu[(long)(m0 + wm + crow + r) * ldc + col1]      = bfu(acc01[r]);
                Cu[(long)(m0 + wm + 16 + crow + r) * ldc + col1] = bfu(acc11[r]);
            }
        }
    } else {
        if (col0 < N) {
            #pragma unroll
            for (int r = 0; r < 4; ++r) {
                C[(long)(m0 + wm + crow + r) * ldc + col0]      = acc00[r];
                C[(long)(m0 + wm + 16 + crow + r) * ldc + col0] = acc10[r];
            }
        }
        if (col1 < N) {
            #pragma unroll
            for (int r = 0; r < 4; ++r) {
                C[(long)(m0 + wm + crow + r) * ldc + col1]      = acc01[r];
                C[(long)(m0 + wm + 16 + crow + r) * ldc + col1] = acc11[r];
            }
        }
    }
}

// ============ MID mega-kernel: indexer + qabs GEMM + pope + mu ===============
// blocks [0,512): indexer (sb=b%16, tb=b/16)     [smem: 26112 B f32]
// blocks [512,1024): qabs bf16-MFMA GEMM          [smem: 10240 B us]
// blocks [1024,1536): pope (2 queries/block)
// blocks [1536,1664): mu
struct MIDARG {
    const float *qIP, *kIP, *w_idx; float* I;
    const float* qc; const unsigned short* wukb; float* qabs;
    const float *qrp, *raw_delta; float* qrr;
    const float* xkr; float* mu;
};

__global__ __launch_bounds__(256) void mid_kernel(MIDARG g)
{
    __shared__ __align__(16) char smem[26112];
    int b = blockIdx.x;
    int t = threadIdx.x;
    if (b < 512) {
        int sb = b % 16, tb = b / 16;
        if (sb * 64 > tb * 32 + 31) return;
        int t0 = tb * 32, s0 = sb * 64;
        float (*ksT)[68] = (float(*)[68])smem;
        float (*qs)[68]  = (float(*)[68])(smem + 17408);
        {
            int r = t & 63, q = t >> 6;
            #pragma unroll
            for (int u = 0; u < 4; ++u) {
                int c4 = q * 4 + u;
                long off = (long)(s0 + r) * 64 + c4 * 4;
                float4 v = *(const float4*)(g.kIP + off);
                #pragma unroll
                for (int s = 1; s < 4; ++s) {
                    float4 v2 = *(const float4*)(g.kIP + (long)s * 65536 + off);
                    v.x += v2.x; v.y += v2.y; v.z += v2.z; v.w += v2.w;
                }
                ksT[c4 * 4 + 0][r] = v.x;
                ksT[c4 * 4 + 1][r] = v.y;
                ksT[c4 * 4 + 2][r] = v.z;
                ksT[c4 * 4 + 3][r] = v.w;
            }
        }
        int ty = t >> 4, tx = t & 15;
        float accI[2][4] = {};
        for (int h = 0; h < 8; ++h) {
            __syncthreads();
            {
                int r = t >> 3, q = t & 7;
                long base = (long)(t0 + r) * 512 + h * 64;
                #pragma unroll
                for (int half = 0; half < 2; ++half) {
                    long off = base + (q + half * 8) * 4;
                    float4 a = *(const float4*)(g.qIP + off);
                    #pragma unroll
                    for (int s = 1; s < 4; ++s) {
                        float4 a1 = *(const float4*)(g.qIP + (long)s * 524288 + off);
                        a.x += a1.x; a.y += a1.y; a.z += a1.z; a.w += a1.w;
                    }
                    *(float4*)&qs[r][(q + half * 8) * 4] = a;
                }
            }
            __syncthreads();
            float acc[2][4] = {};
            #pragma unroll
            for (int dc = 0; dc < 4; ++dc) {
                float a0[16], a1[16];
                #pragma unroll
                for (int u = 0; u < 4; ++u) {
                    float4 v0 = *(float4*)&qs[ty * 2][dc * 16 + u * 4];
                    float4 v1 = *(float4*)&qs[ty * 2 + 1][dc * 16 + u * 4];
                    a0[u * 4 + 0] = v0.x; a0[u * 4 + 1] = v0.y; a0[u * 4 + 2] = v0.z; a0[u * 4 + 3] = v0.w;
                    a1[u * 4 + 0] = v1.x; a1[u * 4 + 1] = v1.y; a1[u * 4 + 2] = v1.z; a1[u * 4 + 3] = v1.w;
                }
                #pragma unroll
                for (int kk = 0; kk < 16; ++kk) {
                    int d = dc * 16 + kk;
                    float4 bb = *(float4*)&ksT[d][tx * 4];
                    acc[0][0] += a0[kk] * bb.x; acc[0][1] += a0[kk] * bb.y;
                    acc[0][2] += a0[kk] * bb.z; acc[0][3] += a0[kk] * bb.w;
                    acc[1][0] += a1[kk] * bb.x; acc[1][1] += a1[kk] * bb.y;
                    acc[1][2] += a1[kk] * bb.z; acc[1][3] += a1[kk] * bb.w;
                }
            }
            float wh = g.w_idx[h];
            #pragma unroll
            for (int i = 0; i < 2; ++i)
                #pragma unroll
                for (int j = 0; j < 4; ++j)
                    accI[i][j] += wh * fmaxf(acc[i][j], 0.f);
        }
        #pragma unroll
        for (int i = 0; i < 2; ++i) {
            float4 v = make_float4(accI[i][0], accI[i][1], accI[i][2], accI[i][3]);
            *(float4*)&g.I[(long)(t0 + ty * 2 + i) * 1024 + s0 + tx * 4] = v;
        }
    } else if (b < 1024) {
        int lb = b - 512;
        int h = lb >> 6, rem = lb & 63;
        int n0 = (rem >> 4) * 64, m0 = (rem & 15) * 64;
        const float* A = g.qc + h * 64;
        const unsigned short* B = g.wukb + h * 64;
        float* C = g.qabs + h * 256;
        unsigned short (*As)[40] = (unsigned short(*)[40])smem;
        unsigned short (*Bs)[40] = (unsigned short(*)[40])(smem + 5120);
        int srow = t >> 2, skq = t & 3;
        int wid = t >> 6, l = t & 63;
        int wm = (wid >> 1) * 32, wn = (wid & 1) * 32;
        int fr = l & 15, fk = (l >> 4) * 8;
        f32x4 acc00 = {0.f, 0.f, 0.f, 0.f};
        f32x4 acc01 = {0.f, 0.f, 0.f, 0.f};
        f32x4 acc10 = {0.f, 0.f, 0.f, 0.f};
        f32x4 acc11 = {0.f, 0.f, 0.f, 0.f};
        for (int k0 = 0; k0 < 64; k0 += 32) {
            {
                const float* ap = A + (long)(m0 + srow) * 512 + k0 + skq * 8;
                float4 v0 = *(const float4*)ap;
                float4 v1 = *(const float4*)(ap + 4);
                unsigned short* d = &As[srow][skq * 8];
                d[0] = bfu(v0.x); d[1] = bfu(v0.y); d[2] = bfu(v0.z); d[3] = bfu(v0.w);
                d[4] = bfu(v1.x); d[5] = bfu(v1.y); d[6] = bfu(v1.z); d[7] = bfu(v1.w);
            }
            {
                uint4 bv = *(const uint4*)(B + (long)(n0 + srow) * 512 + k0 + skq * 8);
                *(uint4*)&Bs[srow][skq * 8] = bv;
            }
            __syncthreads();
            bf16x8 a0 = *(bf16x8*)&As[wm + fr][fk];
            bf16x8 a1 = *(bf16x8*)&As[wm + 16 + fr][fk];
            bf16x8 b0 = *(bf16x8*)&Bs[wn + fr][fk];
            bf16x8 b1 = *(bf16x8*)&Bs[wn + 16 + fr][fk];
            acc00 = __builtin_amdgcn_mfma_f32_16x16x32_bf16(a0, b0, acc00, 0, 0, 0);
            acc01 = __builtin_amdgcn_mfma_f32_16x16x32_bf16(a0, b1, acc01, 0, 0, 0);
            acc10 = __builtin_amdgcn_mfma_f32_16x16x32_bf16(a1, b0, acc10, 0, 0, 0);
            acc11 = __builtin_amdgcn_mfma_f32_16x16x32_bf16(a1, b1, acc11, 0, 0, 0);
            __syncthreads();
        }
        int crow = (l >> 4) * 4;
        int col0 = n0 + wn + fr, col1 = n0 + wn + 16 + fr;
        #pragma unroll
        for (int r = 0; r < 4; ++r) {
            C[(long)(m0 + wm + crow + r) * 2048 + col0]      = acc00[r];
            C[(long)(m0 + wm + 16 + crow + r) * 2048 + col0] = acc10[r];
            C[(long)(m0 + wm + crow + r) * 2048 + col1]      = acc01[r];
            C[(long)(m0 + wm + 16 + crow + r) * 2048 + col1] = acc11[r];
        }
    } else if (b < 1536) {
        int tq = (b - 1024) * 2 + (t >> 7);
        int tt = t & 127;
        int h = tt >> 4, i = tt & 15;
        float rd = g.raw_delta[i];
        float delta = -6.283185307179586f * (1.f / (1.f + expf(-rd)));
        float th = exp2f(-(float)i * 0.83048202372184f);
        float ang = (float)tq * th + delta;
        float sv, cv;
        sincosf(ang, &sv, &cv);
        float m1 = sp_softplus(g.qrp[tq * 256 + h * 32 + i]);
        float m2 = sp_softplus(g.qrp[tq * 256 + h * 32 + 16 + i]);
        g.qrr[tq * 256 + h * 32 + i]      = m1 * cv - m2 * sv;
        g.qrr[tq * 256 + h * 32 + 16 + i] = m1 * sv + m2 * cv;
    } else {
        int i = (b - 1536) * 256 + t;
        g.mu[i] = sp_softplus(g.xkr[i]);
    }
}

// -------- exact top-k (unchanged) ---------------------------------------------
__global__ __launch_bounds__(256) void topk_kernel(
    const float* __restrict__ I, int* __restrict__ idxout)
{
    int t = blockIdx.x * 4 + (threadIdx.x >> 6);
    int lane = threadIdx.x & 63;
    int smin = max(0, t - 63);
    int w = min(64, t + 1);
    if (lane < w) idxout[t * 128 + lane] = smin + lane;
    for (int q = t + 1 + lane; q < 128; q += 64)
        idxout[t * 128 + q] = q;
    int f = max(0, t - 63);
    int m = min(f, 64);
    if (m == 0) return;
    const float* row = I + (long)t * 1024;
    unsigned long long key[16];
    #pragma unroll
    for (int i = 0; i < 16; ++i) {
        int s = i * 64 + lane;
        key[i] = 0ull;
        if (s < f) {
            unsigned u = __float_as_uint(row[s]);
            unsigned ou = (u & 0x80000000u) ? ~u : (u | 0x80000000u);
            key[i] = ((unsigned long long)ou << 32) | (0xFFFFFFFFu - (unsigned)s);
        }
    }
    for (int it = 0; it < m; ++it) {
        unsigned long long best = key[0];
        #pragma unroll
        for (int i = 1; i < 16; ++i) best = key[i] > best ? key[i] : best;
        #pragma unroll
        for (int off = 32; off > 0; off >>= 1) {
            unsigned long long o = __shfl_xor(best, off, 64);
            best = o > best ? o : best;
        }
        int s = (int)(0xFFFFFFFFu - (unsigned)(best & 0xFFFFFFFFull));
        if (lane == 0) idxout[t * 128 + w + it] = s;
        if ((s & 63) == lane) {
            int slot = s >> 6;
            #pragma unroll
            for (int i = 0; i < 16; ++i)
                if (i == slot) key[i] = 0ull;
        }
    }
}

// -------- fused attention v7: bf16 ckv input + 8-way-broadcast PV remap -------
// 256 threads (4 waves), block per query t. LDS ~40.6 KB.
// Numerics bit-identical to v6 (same rounding points, same accumulation order).
__global__ __launch_bounds__(256) void attn_kernel(
    const float* __restrict__ qabs, const float* __restrict__ qrr,
    const unsigned short* __restrict__ ckvb, const float* __restrict__ mu,
    const float* __restrict__ csc, const float* __restrict__ css,
    const int* __restrict__ idxb, float* __restrict__ olat)
{
    __shared__ unsigned short kv[64][296];   // cols 0..255 ckv, 256..287 kr
    __shared__ float sc[8][68];
    __shared__ float hs[16];                 // hs[h]=chunk rescale r; hs[8+h]=lrun
    __shared__ int idx_s[128];

    int t = blockIdx.x, tid = threadIdx.x;
    int w = tid >> 6, l = tid & 63;
    const float scale = 0.10206207261596575f;

    if (tid < 128) idx_s[tid] = idxb[t * 128 + tid];
    {   // stage Q into kv rows 0..15 (consumed into qf before chunk staging)
        int r = tid >> 5;
        for (int c = tid & 31; c < 296; c += 32) {
            float v = 0.f;
            if (c < 256)      v = qabs[(long)t * 2048 + r * 256 + c] * scale;
            else if (c < 288) v = qrr[(long)t * 256 + r * 32 + (c - 256)] * scale;
            kv[r][c] = bfu(v);
            kv[r + 8][c] = 0;
        }
    }
    __syncthreads();

    bf16x8 qf[9];
    #pragma unroll
    for (int ks = 0; ks < 9; ++ks)
        qf[ks] = *(bf16x8*)&kv[l & 15][ks * 32 + (l >> 4) * 8];

    float mrun0 = -INFINITY, mrun1 = -INFINITY;
    float lrun0 = 0.f, lrun1 = 0.f;
    float acc0 = 0, acc1 = 0, acc2 = 0, acc3 = 0;
    float acc4 = 0, acc5 = 0, acc6 = 0, acc7 = 0;

    int sr = tid >> 2, sq = tid & 3;
    int hpv = l >> 3;                 // PV: lane's head (wave covers all 8)
    int c8 = w * 64 + (l & 7) * 8;    // PV: lane's c-octet within wave quarter

    #pragma unroll
    for (int chunk = 0; chunk < 2; ++chunk) {
        __syncthreads();   // prev phase done reading kv
        {   // stage ckv rows (bf16 memcpy: 8 uint4 per thread)
            int src = idx_s[chunk * 64 + sr];
            const uint4* sp = (const uint4*)(ckvb + (long)src * 256) + sq * 8;
            uint4* dp = (uint4*)&kv[sr][0] + sq * 8;
            #pragma unroll
            for (int g = 0; g < 8; ++g) dp[g] = sp[g];
        }
        {   // stage kr cols (PoPE at pos = global slot)
            int src = idx_s[chunk * 64 + sr];
            int j = chunk * 64 + sr;
            unsigned short hh[8];
            #pragma unroll
            for (int ii = 0; ii < 8; ++ii) {
                int i = sq * 8 + ii;
                int i15 = i & 15;
                float m1 = mu[src * 32 + i15];
                float m2 = mu[src * 32 + 16 + i15];
                float cv = csc[j * 16 + i15];
                float sv = css[j * 16 + i15];
                float kr = (i < 16) ? (m1 * cv - m2 * sv) : (m1 * sv + m2 * cv);
                hh[ii] = bfu(kr);
            }
            *(uint4*)&kv[sr][256 + sq * 8] = *(uint4*)hh;
        }
        __syncthreads();

        // QK^T via MFMA: wave w -> slot tile w*16..w*16+15
        f32x4 st = {0.f, 0.f, 0.f, 0.f};
        #pragma unroll
        for (int ks = 0; ks < 9; ++ks) {
            bf16x8 af = *(bf16x8*)&kv[w * 16 + (l & 15)][ks * 32 + (l >> 4) * 8];
            st = __builtin_amdgcn_mfma_f32_16x16x32_bf16(af, qf[ks], st, 0, 0, 0);
        }
        {   // scatter S^T to sc[h][slot]
            int hcol = l & 15;
            int srow2 = w * 16 + (l >> 4) * 4;
            if (hcol < 8) {
                #pragma unroll
                for (int r = 0; r < 4; ++r) sc[hcol][srow2 + r] = st[r];
            }
        }
        __syncthreads();

        // online softmax: wave w handles heads 2w, 2w+1
        float rh0, rh1;
        {
            int h = 2 * w;
            float v = sc[h][l];
            float mx = v;
            #pragma unroll
            for (int off = 32; off > 0; off >>= 1) mx = fmaxf(mx, __shfl_xor(mx, off));
            float mnew = fmaxf(mrun0, mx);
            float p = expf(v - mnew);
            float ps = p;
            #pragma unroll
            for (int off = 32; off > 0; off >>= 1) ps += __shfl_xor(ps, off);
            rh0 = expf(mrun0 - mnew);
            lrun0 = lrun0 * rh0 + ps;
            mrun0 = mnew;
            sc[h][l] = p;
        }
        {
            int h = 2 * w + 1;
            float v = sc[h][l];
            float mx = v;
            #pragma unroll
            for (int off = 32; off > 0; off >>= 1) mx = fmaxf(mx, __shfl_xor(mx, off));
            float mnew = fmaxf(mrun1, mx);
            float p = expf(v - mnew);
            float ps = p;
            #pragma unroll
            for (int off = 32; off > 0; off >>= 1) ps += __shfl_xor(ps, off);
            rh1 = expf(mrun1 - mnew);
            lrun1 = lrun1 * rh1 + ps;
            mrun1 = mnew;
            sc[h][l] = p;
        }
        if (l == 0) {
            hs[2 * w] = rh0;
            hs[2 * w + 1] = rh1;
            if (chunk == 1) {
                hs[8 + 2 * w] = lrun0;
                hs[8 + 2 * w + 1] = lrun1;
            }
        }
        __syncthreads();   // p-rows + hs visible to all waves

        // PV (VALU, 8-way broadcast): lane owns (head hpv, c-octet c8)
        float rsel = hs[hpv];
        acc0 *= rsel; acc1 *= rsel; acc2 *= rsel; acc3 *= rsel;
        acc4 *= rsel; acc5 *= rsel; acc6 *= rsel; acc7 *= rsel;
        #pragma unroll 4
        for (int j = 0; j < 64; ++j) {
            float p = sc[hpv][j];
            uint4 vv = *(uint4*)&kv[j][c8];
            acc0 += p * __uint_as_float(vv.x << 16);
            acc1 += p * __uint_as_float(vv.x & 0xffff0000u);
            acc2 += p * __uint_as_float(vv.y << 16);
            acc3 += p * __uint_as_float(vv.y & 0xffff0000u);
            acc4 += p * __uint_as_float(vv.z << 16);
            acc5 += p * __uint_as_float(vv.z & 0xffff0000u);
            acc6 += p * __uint_as_float(vv.w << 16);
            acc7 += p * __uint_as_float(vv.w & 0xffff0000u);
        }
    }

    float inv = 1.f / hs[8 + hpv];
    float* op = olat + (long)t * 2048 + hpv * 256 + c8;
    *(float4*)op       = make_float4(acc0 * inv, acc1 * inv, acc2 * inv, acc3 * inv);
    *(float4*)(op + 4) = make_float4(acc4 * inv, acc5 * inv, acc6 * inv, acc7 * inv);
}

extern "C" void kernel_launch(void* const* d_in, const int* in_sizes, int n_in,
                              void* d_out, int out_size, void* d_ws, size_t ws_size,
                              hipStream_t stream)
{
    const float* x         = (const float*)d_in[0];
    const float* w_q_idx   = (const float*)d_in[1];
    const float* w_k_idx   = (const float*)d_in[2];
    const float* w_idx     = (const float*)d_in[3];
    const float* raw_delta = (const float*)d_in[4];
    const float* w_dkv     = (const float*)d_in[5];
    const float* w_uk      = (const float*)d_in[6];
    const float* w_uv      = (const float*)d_in[7];
    const float* w_dq      = (const float*)d_in[8];
    const float* w_uq      = (const float*)d_in[9];
    const float* w_qr      = (const float*)d_in[10];
    const float* w_kr      = (const float*)d_in[11];
    const float* w_out     = (const float*)d_in[12];
    (void)in_sizes; (void)n_in; (void)out_size; (void)ws_size;
    float* out = (float*)d_out;

    float* ws = (float*)d_ws;
    unsigned short* ckvb = (unsigned short*)ws;   ws += 131072;   // 1024x256 bf16
    float* cq    = ws;        ws += 1024 * 512;
    float* xkr   = ws;        ws += 1024 * 32;
    float* qrp   = ws;        ws += 1024 * 256;
    float* qrr   = ws;        ws += 1024 * 256;
    float* qc    = ws;        ws += 1024 * 512;
    float* qabs  = ws;        ws += 1024 * 2048;
    float* Ibuf  = ws;        ws += 1024 * 1024;
    int*   idxb  = (int*)ws;  ws += 1024 * 128;
    float* olat  = ws;        ws += 1024 * 2048;
    float* outh  = ws;        ws += 1024 * 512;
    float* mu    = ws;        ws += 1024 * 32;
    float* cscb  = ws;        ws += 128 * 16;
    float* cssb  = ws;        ws += 128 * 16;
    unsigned short* wdkvT = (unsigned short*)ws;  ws += 131072;
    unsigned short* wdqT  = (unsigned short*)ws;  ws += 262144;
    unsigned short* wkrT  = (unsigned short*)ws;  ws += 16384;
    unsigned short* wuqT  = (unsigned short*)ws;  ws += 131072;
    unsigned short* wqrT  = (unsigned short*)ws;  ws += 65536;
    unsigned short* wuvT  = (unsigned short*)ws;  ws += 65536;
    unsigned short* woutT = (unsigned short*)ws;  ws += 262144;
    unsigned short* wukb  = (unsigned short*)ws;  ws += 65536;
    float* part  = ws;        ws += 2359296;
    float* qIP = part;                  // 4 x 524288
    float* kIP = part + 2097152;        // 4 x 65536

    // ---- L1: FRONT (sel GEMM + weight tcast + cs + wukb)
    {
        FRONT f{};
        f.x = x; f.wqidx = w_q_idx; f.wkidx = w_k_idx; f.raw_delta = raw_delta; f.wuk = w_uk;
        f.wdkv = w_dkv; f.wdq = w_dq; f.wkr = w_kr; f.wuq = w_uq; f.wqr = w_qr;
        f.wuv = w_uv; f.wout = w_out;
        f.qIP = qIP; f.kIP = kIP; f.csc = cscb; f.css = cssb;
        f.wdkvT = wdkvT; f.wdqT = wdqT; f.wkrT = wkrT; f.wuqT = wuqT;
        f.wqrT = wqrT; f.wuvT = wuvT; f.woutT = woutT; f.wukb = wukb;
        front_kernel<<<dim3(2136), dim3(256), 0, stream>>>(f);
    }

    // ---- L2: stage-1 value projections: ckv (bf16 out!), cq, xkr
    {
        MFG m{};
        for (int i = 0; i < 3; ++i) { m.A[i]=x; m.lda[i]=1024; m.K[i]=1024; }
        m.B[0]=wdkvT; m.C[0]=(float*)ckvb; m.ldb[0]=1024; m.ldc[0]=256; m.N[0]=256; m.obf[0]=1;
        m.B[1]=wdqT;  m.C[1]=cq;           m.ldb[1]=1024; m.ldc[1]=512; m.N[1]=512;
        m.B[2]=wkrT;  m.C[2]=xkr;          m.ldb[2]=1024; m.ldc[2]=32;  m.N[2]=32;
        m.tstart[0]=0; m.tstart[1]=4; m.tstart[2]=12; m.tstart[3]=13;
        m.ne = 3;
        mgemm<<<dim3(13, 16), dim3(256), 0, stream>>>(m);
    }

    // ---- L3: stage-2: qc, qrp
    {
        MFG m{};
        for (int i = 0; i < 2; ++i) { m.A[i]=cq; m.lda[i]=512; m.K[i]=512; }
        m.B[0]=wuqT; m.C[0]=qc;  m.ldb[0]=512; m.ldc[0]=512; m.N[0]=512;
        m.B[1]=wqrT; m.C[1]=qrp; m.ldb[1]=512; m.ldc[1]=256; m.N[1]=256;
        m.tstart[0]=0; m.tstart[1]=8; m.tstart[2]=12;
        m.ne = 2;
        mgemm<<<dim3(12, 16), dim3(256), 0, stream>>>(m);
    }

    // ---- L4: MID (indexer + qabs + pope + mu, one launch)
    {
        MIDARG g{};
        g.qIP = qIP; g.kIP = kIP; g.w_idx = w_idx; g.I = Ibuf;
        g.qc = qc; g.wukb = wukb; g.qabs = qabs;
        g.qrp = qrp; g.raw_delta = raw_delta; g.qrr = qrr;
        g.xkr = xkr; g.mu = mu;
        mid_kernel<<<dim3(1664), dim3(256), 0, stream>>>(g);
    }

    // ---- L5: exact top-k
    topk_kernel<<<dim3(256), dim3(256), 0, stream>>>(Ibuf, idxb);

    // ---- L6: fused attention v7 -> olat
    attn_kernel<<<dim3(1024), dim3(256), 0, stream>>>(qabs, qrr, ckvb, mu, cscb, cssb, idxb, olat);

    // ---- L7: outh_h = olat_h @ w_uv_h
    {
        MFG m{};
        for (int h = 0; h < 8; ++h) {
            m.A[h] = olat + h * 256;      m.lda[h] = 2048; m.K[h] = 256;
            m.B[h] = wuvT + h * 64 * 256; m.ldb[h] = 256;
            m.C[h] = outh + h * 64;       m.ldc[h] = 512;  m.N[h] = 64;
            m.tstart[h] = h;
        }
        m.tstart[8] = 8;
        m.ne = 8;
        mgemm<<<dim3(8, 16), dim3(256), 0, stream>>>(m);
    }

    // ---- L8: out = outh @ w_out
    {
        MFG m{};
        m.A[0] = outh;  m.lda[0] = 512; m.K[0] = 512;
        m.B[0] = woutT; m.ldb[0] = 512;
        m.C[0] = out;   m.ldc[0] = 1024; m.N[0] = 1024;
        m.tstart[0] = 0; m.tstart[1] = 16;
        m.ne = 1;
        mgemm<<<dim3(16, 16), dim3(256), 0, stream>>>(m);
    }
}

// Round 11
// 194.767 us; speedup vs baseline: 1.2664x; 1.1033x over previous
//
#include <hip/hip_runtime.h>
#include <math.h>

#define S_LEN 1024
#define NH 8

typedef __attribute__((ext_vector_type(8))) short bf16x8;
typedef __attribute__((ext_vector_type(4))) float f32x4;

__device__ __forceinline__ float sp_softplus(float x) {
    return fmaxf(x, 0.f) + log1pf(expf(-fabsf(x)));
}

__device__ __forceinline__ unsigned short bfu(float f) {
    unsigned u = __float_as_uint(f);
    unsigned r = (u + 0x7FFFu + ((u >> 16) & 1u)) >> 16;   // RNE
    return (unsigned short)r;
}

// ============ FRONT mega-kernel: sel-GEMM + weight tcast + cs + wukb =========
struct FRONT {
    const float *x, *wqidx, *wkidx, *raw_delta, *wuk;
    const float *wdkv, *wdq, *wkr, *wuq, *wqr, *wuv, *wout;
    float *qIP, *kIP, *csc, *css;
    unsigned short *wdkvT, *wdqT, *wkrT, *wuqT, *wqrT, *wuvT, *woutT, *wukb;
};

__global__ __launch_bounds__(256) void front_kernel(FRONT f)
{
    __shared__ float As[2][16][18];
    __shared__ float Bs[2][16][68];
    __shared__ unsigned short tile[64][65];
    int bx = blockIdx.x;
    if (bx < 1152) {
        int gx = bx % 18, gy = bx / 18;
        int half = threadIdx.x >> 7;
        int t = threadIdx.x & 127;
        int u = gx * 2 + half;
        const float* B; float* C;
        int ldb, N, n0, kb;
        if (u < 32) {
            B = f.wqidx; ldb = 512; N = 512;
            C = f.qIP + (long)(u >> 3) * 524288;
            n0 = (u & 7) * 64;
            kb = (u >> 3) * 256;
        } else {
            B = f.wkidx; ldb = 64; N = 64;
            C = f.kIP + (long)(u - 32) * 65536;
            n0 = 0;
            kb = (u - 32) * 256;
        }
        int ke = kb + 256;
        int m0 = gy * 16;
        int ar = t >> 2, ak = t & 3;
        int bk = t >> 3, bn = t & 7;
        int ty = t >> 4, tx = t & 15;

        float4 aN = make_float4(0.f, 0.f, 0.f, 0.f);
        if (t < 64) aN = *(const float4*)(f.x + (long)(m0 + ar) * 1024 + kb + ak * 4);
        float4 b0 = *(const float4*)(B + (long)(kb + bk) * ldb + n0 + bn * 4);
        float4 b1 = *(const float4*)(B + (long)(kb + bk) * ldb + n0 + (bn + 8) * 4);
        float acc[2][4] = {};
        for (int k0 = kb; k0 < ke; k0 += 16) {
            if (t < 64) {
                As[half][ak * 4 + 0][ar] = aN.x;
                As[half][ak * 4 + 1][ar] = aN.y;
                As[half][ak * 4 + 2][ar] = aN.z;
                As[half][ak * 4 + 3][ar] = aN.w;
            }
            *(float4*)&Bs[half][bk][bn * 4] = b0;
            *(float4*)&Bs[half][bk][(bn + 8) * 4] = b1;
            __syncthreads();
            if (k0 + 16 < ke) {
                if (t < 64) aN = *(const float4*)(f.x + (long)(m0 + ar) * 1024 + (k0 + 16) + ak * 4);
                b0 = *(const float4*)(B + (long)(k0 + 16 + bk) * ldb + n0 + bn * 4);
                b1 = *(const float4*)(B + (long)(k0 + 16 + bk) * ldb + n0 + (bn + 8) * 4);
            }
            #pragma unroll
            for (int kk = 0; kk < 16; ++kk) {
                float2 a = *(float2*)&As[half][kk][ty * 2];
                float4 b = *(float4*)&Bs[half][kk][tx * 4];
                acc[0][0] += a.x * b.x; acc[0][1] += a.x * b.y;
                acc[0][2] += a.x * b.z; acc[0][3] += a.x * b.w;
                acc[1][0] += a.y * b.x; acc[1][1] += a.y * b.y;
                acc[1][2] += a.y * b.z; acc[1][3] += a.y * b.w;
            }
            __syncthreads();
        }
        #pragma unroll
        for (int i = 0; i < 2; ++i) {
            float4 v = make_float4(acc[i][0], acc[i][1], acc[i][2], acc[i][3]);
            *(float4*)(C + (long)(m0 + ty * 2 + i) * N + n0 + tx * 4) = v;
        }
    } else if (bx < 1616) {
        int b = bx - 1152;
        const float* srcs[7] = {f.wdkv, f.wdq, f.wkr, f.wuq, f.wqr, f.wuv, f.wout};
        unsigned short* dsts[7] = {f.wdkvT, f.wdqT, f.wkrT, f.wuqT, f.wqrT, f.wuvT, f.woutT};
        const int Ns[7]   = {256, 512, 32, 512, 256, 512, 1024};
        const int Klds[7] = {1024, 1024, 1024, 512, 512, 256, 512};
        const int Ntl[7]  = {4, 8, 1, 8, 4, 8, 16};
        const int bst[8]  = {0, 64, 192, 208, 272, 304, 336, 464};
        int e = 0;
        #pragma unroll
        for (int i = 1; i < 7; ++i) if (b >= bst[i]) e = i;
        int lb = b - bst[e];
        int nt = lb % Ntl[e], kt = lb / Ntl[e];
        const float* src = srcs[e];
        unsigned short* dst = dsts[e];
        int N = Ns[e], Kld = Klds[e];
        int k0 = kt * 64, n0 = nt * 64;
        int t = threadIdx.x;
        int c = t & 63, r4 = t >> 6;
        #pragma unroll
        for (int it = 0; it < 16; ++it) {
            int r = it * 4 + r4;
            float v = (n0 + c < N) ? src[(long)(k0 + r) * N + n0 + c] : 0.f;
            tile[r][c] = bfu(v);
        }
        __syncthreads();
        int wq = t & 7;
        #pragma unroll
        for (int itw = 0; itw < 2; ++itw) {
            int wr = itw * 32 + (t >> 3);
            if (n0 + wr < N) {
                unsigned short v[8];
                #pragma unroll
                for (int j = 0; j < 8; ++j) v[j] = tile[wq * 8 + j][wr];
                *(uint4*)(dst + (long)(n0 + wr) * Kld + k0 + wq * 8) = *(uint4*)v;
            }
        }
    } else if (bx < 1624) {
        int idx = (bx - 1616) * 256 + threadIdx.x;
        int j = idx >> 4, i = idx & 15;
        float rd = f.raw_delta[i];
        float delta = -6.283185307179586f * (1.f / (1.f + expf(-rd)));
        float th = exp2f(-(float)i * 0.83048202372184f);
        float ang = (float)j * th + delta;
        float sv, cv;
        sincosf(ang, &sv, &cv);
        f.csc[idx] = cv;
        f.css[idx] = sv;
    } else {
        int idx = (bx - 1624) * 256 + threadIdx.x;
        f.wukb[idx] = bfu(f.wuk[idx]);
    }
}

// ============ bf16 MFMA routed multi-GEMM (+ per-entry bf16 output) ==========
struct MFG {
    const float* A[10]; const unsigned short* B[10]; float* C[10];
    int lda[10], ldb[10], ldc[10], K[10], N[10], obf[10];
    int tstart[11]; int ne;
};

__global__ __launch_bounds__(256) void mgemm(MFG mg)
{
    int bx = blockIdx.x, e = 0;
    #pragma unroll
    for (int i = 1; i < 10; ++i) if (i < mg.ne && bx >= mg.tstart[i]) e = i;
    const float* A = mg.A[e];
    const unsigned short* B = mg.B[e];
    float* C = mg.C[e];
    int lda = mg.lda[e], ldb = mg.ldb[e], ldc = mg.ldc[e];
    int K = mg.K[e], N = mg.N[e];
    int m0 = blockIdx.y * 64, n0 = (bx - mg.tstart[e]) * 64;

    __shared__ unsigned short As[64][40];
    __shared__ unsigned short Bs[64][40];
    int t = threadIdx.x;
    int srow = t >> 2, skq = t & 3;
    int wid = t >> 6, l = t & 63;
    int wm = (wid >> 1) * 32, wn = (wid & 1) * 32;
    int fr = l & 15, fk = (l >> 4) * 8;
    bool bok = (n0 + srow) < N;

    f32x4 acc00 = {0.f, 0.f, 0.f, 0.f};
    f32x4 acc01 = {0.f, 0.f, 0.f, 0.f};
    f32x4 acc10 = {0.f, 0.f, 0.f, 0.f};
    f32x4 acc11 = {0.f, 0.f, 0.f, 0.f};

    for (int k0 = 0; k0 < K; k0 += 32) {
        {
            const float* ap = A + (long)(m0 + srow) * lda + k0 + skq * 8;
            float4 v0 = *(const float4*)ap;
            float4 v1 = *(const float4*)(ap + 4);
            unsigned short* d = &As[srow][skq * 8];
            d[0] = bfu(v0.x); d[1] = bfu(v0.y); d[2] = bfu(v0.z); d[3] = bfu(v0.w);
            d[4] = bfu(v1.x); d[5] = bfu(v1.y); d[6] = bfu(v1.z); d[7] = bfu(v1.w);
        }
        {
            uint4 bv = make_uint4(0u, 0u, 0u, 0u);
            if (bok) bv = *(const uint4*)(B + (long)(n0 + srow) * ldb + k0 + skq * 8);
            *(uint4*)&Bs[srow][skq * 8] = bv;
        }
        __syncthreads();
        bf16x8 a0 = *(bf16x8*)&As[wm + fr][fk];
        bf16x8 a1 = *(bf16x8*)&As[wm + 16 + fr][fk];
        bf16x8 b0 = *(bf16x8*)&Bs[wn + fr][fk];
        bf16x8 b1 = *(bf16x8*)&Bs[wn + 16 + fr][fk];
        acc00 = __builtin_amdgcn_mfma_f32_16x16x32_bf16(a0, b0, acc00, 0, 0, 0);
        acc01 = __builtin_amdgcn_mfma_f32_16x16x32_bf16(a0, b1, acc01, 0, 0, 0);
        acc10 = __builtin_amdgcn_mfma_f32_16x16x32_bf16(a1, b0, acc10, 0, 0, 0);
        acc11 = __builtin_amdgcn_mfma_f32_16x16x32_bf16(a1, b1, acc11, 0, 0, 0);
        __syncthreads();
    }
    int crow = (l >> 4) * 4;
    int col0 = n0 + wn + fr, col1 = n0 + wn + 16 + fr;
    if (mg.obf[e]) {
        unsigned short* Cu = (unsigned short*)C;
        if (col0 < N) {
            #pragma unroll
            for (int r = 0; r < 4; ++r) {
                Cu[(long)(m0 + wm + crow + r) * ldc + col0]      = bfu(acc00[r]);
                Cu[(long)(m0 + wm + 16 + crow + r) * ldc + col0] = bfu(acc10[r]);
            }
        }
        if (col1 < N) {
            #pragma unroll
            for (int r = 0; r < 4; ++r) {
                Cu[(long)(m0 + wm + crow + r) * ldc + col1]      = bfu(acc01[r]);
                Cu[(long)(m0 + wm + 16 + crow + r) * ldc + col1] = bfu(acc11[r]);
            }
        }
    } else {
        if (col0 < N) {
            #pragma unroll
            for (int r = 0; r < 4; ++r) {
                C[(long)(m0 + wm + crow + r) * ldc + col0]      = acc00[r];
                C[(long)(m0 + wm + 16 + crow + r) * ldc + col0] = acc10[r];
            }
        }
        if (col1 < N) {
            #pragma unroll
            for (int r = 0; r < 4; ++r) {
                C[(long)(m0 + wm + crow + r) * ldc + col1]      = acc01[r];
                C[(long)(m0 + wm + 16 + crow + r) * ldc + col1] = acc11[r];
            }
        }
    }
}

// ============ MID mega-kernel: indexer + qabs GEMM + pope + mu ===============
struct MIDARG {
    const float *qIP, *kIP, *w_idx; float* I;
    const float* qc; const unsigned short* wukb; float* qabs;
    const float *qrp, *raw_delta; float* qrr;
    const float* xkr; float* mu;
};

__global__ __launch_bounds__(256) void mid_kernel(MIDARG g)
{
    __shared__ __align__(16) char smem[26112];
    int b = blockIdx.x;
    int t = threadIdx.x;
    if (b < 512) {
        int sb = b % 16, tb = b / 16;
        if (sb * 64 > tb * 32 + 31) return;
        int t0 = tb * 32, s0 = sb * 64;
        float (*ksT)[68] = (float(*)[68])smem;
        float (*qs)[68]  = (float(*)[68])(smem + 17408);
        {
            int r = t & 63, q = t >> 6;
            #pragma unroll
            for (int u = 0; u < 4; ++u) {
                int c4 = q * 4 + u;
                long off = (long)(s0 + r) * 64 + c4 * 4;
                float4 v = *(const float4*)(g.kIP + off);
                #pragma unroll
                for (int s = 1; s < 4; ++s) {
                    float4 v2 = *(const float4*)(g.kIP + (long)s * 65536 + off);
                    v.x += v2.x; v.y += v2.y; v.z += v2.z; v.w += v2.w;
                }
                ksT[c4 * 4 + 0][r] = v.x;
                ksT[c4 * 4 + 1][r] = v.y;
                ksT[c4 * 4 + 2][r] = v.z;
                ksT[c4 * 4 + 3][r] = v.w;
            }
        }
        int ty = t >> 4, tx = t & 15;
        float accI[2][4] = {};
        for (int h = 0; h < 8; ++h) {
            __syncthreads();
            {
                int r = t >> 3, q = t & 7;
                long base = (long)(t0 + r) * 512 + h * 64;
                #pragma unroll
                for (int half = 0; half < 2; ++half) {
                    long off = base + (q + half * 8) * 4;
                    float4 a = *(const float4*)(g.qIP + off);
                    #pragma unroll
                    for (int s = 1; s < 4; ++s) {
                        float4 a1 = *(const float4*)(g.qIP + (long)s * 524288 + off);
                        a.x += a1.x; a.y += a1.y; a.z += a1.z; a.w += a1.w;
                    }
                    *(float4*)&qs[r][(q + half * 8) * 4] = a;
                }
            }
            __syncthreads();
            float acc[2][4] = {};
            #pragma unroll
            for (int dc = 0; dc < 4; ++dc) {
                float a0[16], a1[16];
                #pragma unroll
                for (int u = 0; u < 4; ++u) {
                    float4 v0 = *(float4*)&qs[ty * 2][dc * 16 + u * 4];
                    float4 v1 = *(float4*)&qs[ty * 2 + 1][dc * 16 + u * 4];
                    a0[u * 4 + 0] = v0.x; a0[u * 4 + 1] = v0.y; a0[u * 4 + 2] = v0.z; a0[u * 4 + 3] = v0.w;
                    a1[u * 4 + 0] = v1.x; a1[u * 4 + 1] = v1.y; a1[u * 4 + 2] = v1.z; a1[u * 4 + 3] = v1.w;
                }
                #pragma unroll
                for (int kk = 0; kk < 16; ++kk) {
                    int d = dc * 16 + kk;
                    float4 bb = *(float4*)&ksT[d][tx * 4];
                    acc[0][0] += a0[kk] * bb.x; acc[0][1] += a0[kk] * bb.y;
                    acc[0][2] += a0[kk] * bb.z; acc[0][3] += a0[kk] * bb.w;
                    acc[1][0] += a1[kk] * bb.x; acc[1][1] += a1[kk] * bb.y;
                    acc[1][2] += a1[kk] * bb.z; acc[1][3] += a1[kk] * bb.w;
                }
            }
            float wh = g.w_idx[h];
            #pragma unroll
            for (int i = 0; i < 2; ++i)
                #pragma unroll
                for (int j = 0; j < 4; ++j)
                    accI[i][j] += wh * fmaxf(acc[i][j], 0.f);
        }
        #pragma unroll
        for (int i = 0; i < 2; ++i) {
            float4 v = make_float4(accI[i][0], accI[i][1], accI[i][2], accI[i][3]);
            *(float4*)&g.I[(long)(t0 + ty * 2 + i) * 1024 + s0 + tx * 4] = v;
        }
    } else if (b < 1024) {
        int lb = b - 512;
        int h = lb >> 6, rem = lb & 63;
        int n0 = (rem >> 4) * 64, m0 = (rem & 15) * 64;
        const float* A = g.qc + h * 64;
        const unsigned short* B = g.wukb + h * 64;
        float* C = g.qabs + h * 256;
        unsigned short (*As)[40] = (unsigned short(*)[40])smem;
        unsigned short (*Bs)[40] = (unsigned short(*)[40])(smem + 5120);
        int srow = t >> 2, skq = t & 3;
        int wid = t >> 6, l = t & 63;
        int wm = (wid >> 1) * 32, wn = (wid & 1) * 32;
        int fr = l & 15, fk = (l >> 4) * 8;
        f32x4 acc00 = {0.f, 0.f, 0.f, 0.f};
        f32x4 acc01 = {0.f, 0.f, 0.f, 0.f};
        f32x4 acc10 = {0.f, 0.f, 0.f, 0.f};
        f32x4 acc11 = {0.f, 0.f, 0.f, 0.f};
        for (int k0 = 0; k0 < 64; k0 += 32) {
            {
                const float* ap = A + (long)(m0 + srow) * 512 + k0 + skq * 8;
                float4 v0 = *(const float4*)ap;
                float4 v1 = *(const float4*)(ap + 4);
                unsigned short* d = &As[srow][skq * 8];
                d[0] = bfu(v0.x); d[1] = bfu(v0.y); d[2] = bfu(v0.z); d[3] = bfu(v0.w);
                d[4] = bfu(v1.x); d[5] = bfu(v1.y); d[6] = bfu(v1.z); d[7] = bfu(v1.w);
            }
            {
                uint4 bv = *(const uint4*)(B + (long)(n0 + srow) * 512 + k0 + skq * 8);
                *(uint4*)&Bs[srow][skq * 8] = bv;
            }
            __syncthreads();
            bf16x8 a0 = *(bf16x8*)&As[wm + fr][fk];
            bf16x8 a1 = *(bf16x8*)&As[wm + 16 + fr][fk];
            bf16x8 b0 = *(bf16x8*)&Bs[wn + fr][fk];
            bf16x8 b1 = *(bf16x8*)&Bs[wn + 16 + fr][fk];
            acc00 = __builtin_amdgcn_mfma_f32_16x16x32_bf16(a0, b0, acc00, 0, 0, 0);
            acc01 = __builtin_amdgcn_mfma_f32_16x16x32_bf16(a0, b1, acc01, 0, 0, 0);
            acc10 = __builtin_amdgcn_mfma_f32_16x16x32_bf16(a1, b0, acc10, 0, 0, 0);
            acc11 = __builtin_amdgcn_mfma_f32_16x16x32_bf16(a1, b1, acc11, 0, 0, 0);
            __syncthreads();
        }
        int crow = (l >> 4) * 4;
        int col0 = n0 + wn + fr, col1 = n0 + wn + 16 + fr;
        #pragma unroll
        for (int r = 0; r < 4; ++r) {
            C[(long)(m0 + wm + crow + r) * 2048 + col0]      = acc00[r];
            C[(long)(m0 + wm + 16 + crow + r) * 2048 + col0] = acc10[r];
            C[(long)(m0 + wm + crow + r) * 2048 + col1]      = acc01[r];
            C[(long)(m0 + wm + 16 + crow + r) * 2048 + col1] = acc11[r];
        }
    } else if (b < 1536) {
        int tq = (b - 1024) * 2 + (t >> 7);
        int tt = t & 127;
        int h = tt >> 4, i = tt & 15;
        float rd = g.raw_delta[i];
        float delta = -6.283185307179586f * (1.f / (1.f + expf(-rd)));
        float th = exp2f(-(float)i * 0.83048202372184f);
        float ang = (float)tq * th + delta;
        float sv, cv;
        sincosf(ang, &sv, &cv);
        float m1 = sp_softplus(g.qrp[tq * 256 + h * 32 + i]);
        float m2 = sp_softplus(g.qrp[tq * 256 + h * 32 + 16 + i]);
        g.qrr[tq * 256 + h * 32 + i]      = m1 * cv - m2 * sv;
        g.qrr[tq * 256 + h * 32 + 16 + i] = m1 * sv + m2 * cv;
    } else {
        int i = (b - 1536) * 256 + t;
        g.mu[i] = sp_softplus(g.xkr[i]);
    }
}

// -------- exact top-k v2: full wave bitonic sort of 1024 64-bit keys ---------
// One wave per row; element id i = lane*16 + r. Keys: (ordered_float<<32) |
// (0xFFFFFFFF - s); invalid s -> 0 (sinks in descending sort). Descending
// order == jax.lax.top_k order (value desc, ties index asc) — selection
// bit-identical to the iterative extraction it replaces.
__global__ __launch_bounds__(256) void topk_kernel(
    const float* __restrict__ I, int* __restrict__ idxout)
{
    int t = blockIdx.x * 4 + (threadIdx.x >> 6);
    int lane = threadIdx.x & 63;
    int smin = max(0, t - 63);
    int w = min(64, t + 1);                 // +inf local-window entries
    if (lane < w) idxout[t * 128 + lane] = smin + lane;
    for (int q = t + 1 + lane; q < 128; q += 64)   // -inf future fill
        idxout[t * 128 + q] = q;
    int f = max(0, t - 63);                 // finite candidates: s in [0, f)
    int m = min(f, 64);
    if (m == 0) return;
    const float* row = I + (long)t * 1024;

    unsigned long long key[16];
    #pragma unroll
    for (int g4 = 0; g4 < 4; ++g4) {
        float4 v = *(const float4*)(row + lane * 16 + g4 * 4);
        float vv[4] = {v.x, v.y, v.z, v.w};
        #pragma unroll
        for (int j = 0; j < 4; ++j) {
            int s = lane * 16 + g4 * 4 + j;
            unsigned long long k = 0ull;
            if (s < f) {
                unsigned u = __float_as_uint(vv[j]);
                unsigned ou = (u & 0x80000000u) ? ~u : (u | 0x80000000u);
                k = ((unsigned long long)ou << 32) | (0xFFFFFFFFu - (unsigned)s);
            }
            key[g4 * 4 + j] = k;
        }
    }

    // bitonic sort, 1024 elements, DESCENDING. i = lane*16 + r.
    #pragma unroll
    for (int km = 1; km <= 10; ++km) {          // k = 1<<km
        #pragma unroll
        for (int jm = km - 1; jm >= 0; --jm) {  // j = 1<<jm
            if (jm >= 4) {
                int lmask = 1 << (jm - 4);
                #pragma unroll
                for (int r = 0; r < 16; ++r) {
                    unsigned long long other = __shfl_xor(key[r], lmask, 64);
                    int i = lane * 16 + r;
                    bool keep_max = (((i & (1 << km)) == 0) == ((i & (1 << jm)) == 0));
                    unsigned long long mx = key[r] > other ? key[r] : other;
                    unsigned long long mn = key[r] > other ? other : key[r];
                    key[r] = keep_max ? mx : mn;
                }
            } else {
                int rmask = 1 << jm;
                #pragma unroll
                for (int r = 0; r < 16; ++r) {
                    if ((r & rmask) == 0) {
                        int r2 = r | rmask;
                        int i = lane * 16 + r;
                        bool keep_max_low = ((i & (1 << km)) == 0);
                        unsigned long long a = key[r], b = key[r2];
                        unsigned long long mx = a > b ? a : b;
                        unsigned long long mn = a > b ? b : a;
                        key[r]  = keep_max_low ? mx : mn;
                        key[r2] = keep_max_low ? mn : mx;
                    }
                }
            }
        }
    }

    // element e (= lane*16+r) holds the e-th largest; write top-m in order
    if (lane < 4) {
        #pragma unroll
        for (int r = 0; r < 16; ++r) {
            int e = lane * 16 + r;
            if (e < m) {
                int s = (int)(0xFFFFFFFFu - (unsigned)(key[r] & 0xFFFFFFFFull));
                idxout[t * 128 + w + e] = s;
            }
        }
    }
}

// -------- fused attention v7 (unchanged from r10) -----------------------------
__global__ __launch_bounds__(256) void attn_kernel(
    const float* __restrict__ qabs, const float* __restrict__ qrr,
    const unsigned short* __restrict__ ckvb, const float* __restrict__ mu,
    const float* __restrict__ csc, const float* __restrict__ css,
    const int* __restrict__ idxb, float* __restrict__ olat)
{
    __shared__ unsigned short kv[64][296];
    __shared__ float sc[8][68];
    __shared__ float hs[16];
    __shared__ int idx_s[128];

    int t = blockIdx.x, tid = threadIdx.x;
    int w = tid >> 6, l = tid & 63;
    const float scale = 0.10206207261596575f;

    if (tid < 128) idx_s[tid] = idxb[t * 128 + tid];
    {
        int r = tid >> 5;
        for (int c = tid & 31; c < 296; c += 32) {
            float v = 0.f;
            if (c < 256)      v = qabs[(long)t * 2048 + r * 256 + c] * scale;
            else if (c < 288) v = qrr[(long)t * 256 + r * 32 + (c - 256)] * scale;
            kv[r][c] = bfu(v);
            kv[r + 8][c] = 0;
        }
    }
    __syncthreads();

    bf16x8 qf[9];
    #pragma unroll
    for (int ks = 0; ks < 9; ++ks)
        qf[ks] = *(bf16x8*)&kv[l & 15][ks * 32 + (l >> 4) * 8];

    float mrun0 = -INFINITY, mrun1 = -INFINITY;
    float lrun0 = 0.f, lrun1 = 0.f;
    float acc0 = 0, acc1 = 0, acc2 = 0, acc3 = 0;
    float acc4 = 0, acc5 = 0, acc6 = 0, acc7 = 0;

    int sr = tid >> 2, sq = tid & 3;
    int hpv = l >> 3;
    int c8 = w * 64 + (l & 7) * 8;

    #pragma unroll
    for (int chunk = 0; chunk < 2; ++chunk) {
        __syncthreads();
        {
            int src = idx_s[chunk * 64 + sr];
            const uint4* sp = (const uint4*)(ckvb + (long)src * 256) + sq * 8;
            uint4* dp = (uint4*)&kv[sr][0] + sq * 8;
            #pragma unroll
            for (int g = 0; g < 8; ++g) dp[g] = sp[g];
        }
        {
            int src = idx_s[chunk * 64 + sr];
            int j = chunk * 64 + sr;
            unsigned short hh[8];
            #pragma unroll
            for (int ii = 0; ii < 8; ++ii) {
                int i = sq * 8 + ii;
                int i15 = i & 15;
                float m1 = mu[src * 32 + i15];
                float m2 = mu[src * 32 + 16 + i15];
                float cv = csc[j * 16 + i15];
                float sv = css[j * 16 + i15];
                float kr = (i < 16) ? (m1 * cv - m2 * sv) : (m1 * sv + m2 * cv);
                hh[ii] = bfu(kr);
            }
            *(uint4*)&kv[sr][256 + sq * 8] = *(uint4*)hh;
        }
        __syncthreads();

        f32x4 st = {0.f, 0.f, 0.f, 0.f};
        #pragma unroll
        for (int ks = 0; ks < 9; ++ks) {
            bf16x8 af = *(bf16x8*)&kv[w * 16 + (l & 15)][ks * 32 + (l >> 4) * 8];
            st = __builtin_amdgcn_mfma_f32_16x16x32_bf16(af, qf[ks], st, 0, 0, 0);
        }
        {
            int hcol = l & 15;
            int srow2 = w * 16 + (l >> 4) * 4;
            if (hcol < 8) {
                #pragma unroll
                for (int r = 0; r < 4; ++r) sc[hcol][srow2 + r] = st[r];
            }
        }
        __syncthreads();

        float rh0, rh1;
        {
            int h = 2 * w;
            float v = sc[h][l];
            float mx = v;
            #pragma unroll
            for (int off = 32; off > 0; off >>= 1) mx = fmaxf(mx, __shfl_xor(mx, off));
            float mnew = fmaxf(mrun0, mx);
            float p = expf(v - mnew);
            float ps = p;
            #pragma unroll
            for (int off = 32; off > 0; off >>= 1) ps += __shfl_xor(ps, off);
            rh0 = expf(mrun0 - mnew);
            lrun0 = lrun0 * rh0 + ps;
            mrun0 = mnew;
            sc[h][l] = p;
        }
        {
            int h = 2 * w + 1;
            float v = sc[h][l];
            float mx = v;
            #pragma unroll
            for (int off = 32; off > 0; off >>= 1) mx = fmaxf(mx, __shfl_xor(mx, off));
            float mnew = fmaxf(mrun1, mx);
            float p = expf(v - mnew);
            float ps = p;
            #pragma unroll
            for (int off = 32; off > 0; off >>= 1) ps += __shfl_xor(ps, off);
            rh1 = expf(mrun1 - mnew);
            lrun1 = lrun1 * rh1 + ps;
            mrun1 = mnew;
            sc[h][l] = p;
        }
        if (l == 0) {
            hs[2 * w] = rh0;
            hs[2 * w + 1] = rh1;
            if (chunk == 1) {
                hs[8 + 2 * w] = lrun0;
                hs[8 + 2 * w + 1] = lrun1;
            }
        }
        __syncthreads();

        float rsel = hs[hpv];
        acc0 *= rsel; acc1 *= rsel; acc2 *= rsel; acc3 *= rsel;
        acc4 *= rsel; acc5 *= rsel; acc6 *= rsel; acc7 *= rsel;
        #pragma unroll 4
        for (int j = 0; j < 64; ++j) {
            float p = sc[hpv][j];
            uint4 vv = *(uint4*)&kv[j][c8];
            acc0 += p * __uint_as_float(vv.x << 16);
            acc1 += p * __uint_as_float(vv.x & 0xffff0000u);
            acc2 += p * __uint_as_float(vv.y << 16);
            acc3 += p * __uint_as_float(vv.y & 0xffff0000u);
            acc4 += p * __uint_as_float(vv.z << 16);
            acc5 += p * __uint_as_float(vv.z & 0xffff0000u);
            acc6 += p * __uint_as_float(vv.w << 16);
            acc7 += p * __uint_as_float(vv.w & 0xffff0000u);
        }
    }

    float inv = 1.f / hs[8 + hpv];
    float* op = olat + (long)t * 2048 + hpv * 256 + c8;
    *(float4*)op       = make_float4(acc0 * inv, acc1 * inv, acc2 * inv, acc3 * inv);
    *(float4*)(op + 4) = make_float4(acc4 * inv, acc5 * inv, acc6 * inv, acc7 * inv);
}

extern "C" void kernel_launch(void* const* d_in, const int* in_sizes, int n_in,
                              void* d_out, int out_size, void* d_ws, size_t ws_size,
                              hipStream_t stream)
{
    const float* x         = (const float*)d_in[0];
    const float* w_q_idx   = (const float*)d_in[1];
    const float* w_k_idx   = (const float*)d_in[2];
    const float* w_idx     = (const float*)d_in[3];
    const float* raw_delta = (const float*)d_in[4];
    const float* w_dkv     = (const float*)d_in[5];
    const float* w_uk      = (const float*)d_in[6];
    const float* w_uv      = (const float*)d_in[7];
    const float* w_dq      = (const float*)d_in[8];
    const float* w_uq      = (const float*)d_in[9];
    const float* w_qr      = (const float*)d_in[10];
    const float* w_kr      = (const float*)d_in[11];
    const float* w_out     = (const float*)d_in[12];
    (void)in_sizes; (void)n_in; (void)out_size; (void)ws_size;
    float* out = (float*)d_out;

    float* ws = (float*)d_ws;
    unsigned short* ckvb = (unsigned short*)ws;   ws += 131072;   // 1024x256 bf16
    float* cq    = ws;        ws += 1024 * 512;
    float* xkr   = ws;        ws += 1024 * 32;
    float* qrp   = ws;        ws += 1024 * 256;
    float* qrr   = ws;        ws += 1024 * 256;
    float* qc    = ws;        ws += 1024 * 512;
    float* qabs  = ws;        ws += 1024 * 2048;
    float* Ibuf  = ws;        ws += 1024 * 1024;
    int*   idxb  = (int*)ws;  ws += 1024 * 128;
    float* olat  = ws;        ws += 1024 * 2048;
    float* outh  = ws;        ws += 1024 * 512;
    float* mu    = ws;        ws += 1024 * 32;
    float* cscb  = ws;        ws += 128 * 16;
    float* cssb  = ws;        ws += 128 * 16;
    unsigned short* wdkvT = (unsigned short*)ws;  ws += 131072;
    unsigned short* wdqT  = (unsigned short*)ws;  ws += 262144;
    unsigned short* wkrT  = (unsigned short*)ws;  ws += 16384;
    unsigned short* wuqT  = (unsigned short*)ws;  ws += 131072;
    unsigned short* wqrT  = (unsigned short*)ws;  ws += 65536;
    unsigned short* wuvT  = (unsigned short*)ws;  ws += 65536;
    unsigned short* woutT = (unsigned short*)ws;  ws += 262144;
    unsigned short* wukb  = (unsigned short*)ws;  ws += 65536;
    float* part  = ws;        ws += 2359296;
    float* qIP = part;                  // 4 x 524288
    float* kIP = part + 2097152;        // 4 x 65536

    // ---- L1: FRONT (sel GEMM + weight tcast + cs + wukb)
    {
        FRONT f{};
        f.x = x; f.wqidx = w_q_idx; f.wkidx = w_k_idx; f.raw_delta = raw_delta; f.wuk = w_uk;
        f.wdkv = w_dkv; f.wdq = w_dq; f.wkr = w_kr; f.wuq = w_uq; f.wqr = w_qr;
        f.wuv = w_uv; f.wout = w_out;
        f.qIP = qIP; f.kIP = kIP; f.csc = cscb; f.css = cssb;
        f.wdkvT = wdkvT; f.wdqT = wdqT; f.wkrT = wkrT; f.wuqT = wuqT;
        f.wqrT = wqrT; f.wuvT = wuvT; f.woutT = woutT; f.wukb = wukb;
        front_kernel<<<dim3(2136), dim3(256), 0, stream>>>(f);
    }

    // ---- L2: stage-1 value projections: ckv (bf16 out), cq, xkr
    {
        MFG m{};
        for (int i = 0; i < 3; ++i) { m.A[i]=x; m.lda[i]=1024; m.K[i]=1024; }
        m.B[0]=wdkvT; m.C[0]=(float*)ckvb; m.ldb[0]=1024; m.ldc[0]=256; m.N[0]=256; m.obf[0]=1;
        m.B[1]=wdqT;  m.C[1]=cq;           m.ldb[1]=1024; m.ldc[1]=512; m.N[1]=512;
        m.B[2]=wkrT;  m.C[2]=xkr;          m.ldb[2]=1024; m.ldc[2]=32;  m.N[2]=32;
        m.tstart[0]=0; m.tstart[1]=4; m.tstart[2]=12; m.tstart[3]=13;
        m.ne = 3;
        mgemm<<<dim3(13, 16), dim3(256), 0, stream>>>(m);
    }

    // ---- L3: stage-2: qc, qrp
    {
        MFG m{};
        for (int i = 0; i < 2; ++i) { m.A[i]=cq; m.lda[i]=512; m.K[i]=512; }
        m.B[0]=wuqT; m.C[0]=qc;  m.ldb[0]=512; m.ldc[0]=512; m.N[0]=512;
        m.B[1]=wqrT; m.C[1]=qrp; m.ldb[1]=512; m.ldc[1]=256; m.N[1]=256;
        m.tstart[0]=0; m.tstart[1]=8; m.tstart[2]=12;
        m.ne = 2;
        mgemm<<<dim3(12, 16), dim3(256), 0, stream>>>(m);
    }

    // ---- L4: MID (indexer + qabs + pope + mu)
    {
        MIDARG g{};
        g.qIP = qIP; g.kIP = kIP; g.w_idx = w_idx; g.I = Ibuf;
        g.qc = qc; g.wukb = wukb; g.qabs = qabs;
        g.qrp = qrp; g.raw_delta = raw_delta; g.qrr = qrr;
        g.xkr = xkr; g.mu = mu;
        mid_kernel<<<dim3(1664), dim3(256), 0, stream>>>(g);
    }

    // ---- L5: exact top-k (bitonic)
    topk_kernel<<<dim3(256), dim3(256), 0, stream>>>(Ibuf, idxb);

    // ---- L6: fused attention v7 -> olat
    attn_kernel<<<dim3(1024), dim3(256), 0, stream>>>(qabs, qrr, ckvb, mu, cscb, cssb, idxb, olat);

    // ---- L7: outh_h = olat_h @ w_uv_h
    {
        MFG m{};
        for (int h = 0; h < 8; ++h) {
            m.A[h] = olat + h * 256;      m.lda[h] = 2048; m.K[h] = 256;
            m.B[h] = wuvT + h * 64 * 256; m.ldb[h] = 256;
            m.C[h] = outh + h * 64;       m.ldc[h] = 512;  m.N[h] = 64;
            m.tstart[h] = h;
        }
        m.tstart[8] = 8;
        m.ne = 8;
        mgemm<<<dim3(8, 16), dim3(256), 0, stream>>>(m);
    }

    // ---- L8: out = outh @ w_out
    {
        MFG m{};
        m.A[0] = outh;  m.lda[0] = 512; m.K[0] = 512;
        m.B[0] = woutT; m.ldb[0] = 512;
        m.C[0] = out;   m.ldc[0] = 1024; m.N[0] = 1024;
        m.tstart[0] = 0; m.tstart[1] = 16;
        m.ne = 1;
        mgemm<<<dim3(16, 16), dim3(256), 0, stream>>>(m);
    }
}

// Round 12
// 193.808 us; speedup vs baseline: 1.2727x; 1.0049x over previous
//
#include <hip/hip_runtime.h>
#include <math.h>

#define S_LEN 1024
#define NH 8

typedef __attribute__((ext_vector_type(8))) short bf16x8;
typedef __attribute__((ext_vector_type(4))) float f32x4;

__device__ __forceinline__ float sp_softplus(float x) {
    return fmaxf(x, 0.f) + log1pf(expf(-fabsf(x)));
}

__device__ __forceinline__ unsigned short bfu(float f) {
    unsigned u = __float_as_uint(f);
    unsigned r = (u + 0x7FFFu + ((u >> 16) & 1u)) >> 16;   // RNE
    return (unsigned short)r;
}

// ============ FRONT mega-kernel: sel-GEMM + weight tcast + cs + wukb =========
struct FRONT {
    const float *x, *wqidx, *wkidx, *raw_delta, *wuk;
    const float *wdkv, *wdq, *wkr, *wuq, *wqr, *wuv, *wout;
    float *qIP, *kIP, *csc, *css;
    unsigned short *wdkvT, *wdqT, *wkrT, *wuqT, *wqrT, *wuvT, *woutT, *wukb;
};

__global__ __launch_bounds__(256) void front_kernel(FRONT f)
{
    __shared__ float As[2][16][18];
    __shared__ float Bs[2][16][68];
    __shared__ unsigned short tile[64][65];
    int bx = blockIdx.x;
    if (bx < 1152) {
        int gx = bx % 18, gy = bx / 18;
        int half = threadIdx.x >> 7;
        int t = threadIdx.x & 127;
        int u = gx * 2 + half;
        const float* B; float* C;
        int ldb, N, n0, kb;
        if (u < 32) {
            B = f.wqidx; ldb = 512; N = 512;
            C = f.qIP + (long)(u >> 3) * 524288;
            n0 = (u & 7) * 64;
            kb = (u >> 3) * 256;
        } else {
            B = f.wkidx; ldb = 64; N = 64;
            C = f.kIP + (long)(u - 32) * 65536;
            n0 = 0;
            kb = (u - 32) * 256;
        }
        int ke = kb + 256;
        int m0 = gy * 16;
        int ar = t >> 2, ak = t & 3;
        int bk = t >> 3, bn = t & 7;
        int ty = t >> 4, tx = t & 15;

        float4 aN = make_float4(0.f, 0.f, 0.f, 0.f);
        if (t < 64) aN = *(const float4*)(f.x + (long)(m0 + ar) * 1024 + kb + ak * 4);
        float4 b0 = *(const float4*)(B + (long)(kb + bk) * ldb + n0 + bn * 4);
        float4 b1 = *(const float4*)(B + (long)(kb + bk) * ldb + n0 + (bn + 8) * 4);
        float acc[2][4] = {};
        for (int k0 = kb; k0 < ke; k0 += 16) {
            if (t < 64) {
                As[half][ak * 4 + 0][ar] = aN.x;
                As[half][ak * 4 + 1][ar] = aN.y;
                As[half][ak * 4 + 2][ar] = aN.z;
                As[half][ak * 4 + 3][ar] = aN.w;
            }
            *(float4*)&Bs[half][bk][bn * 4] = b0;
            *(float4*)&Bs[half][bk][(bn + 8) * 4] = b1;
            __syncthreads();
            if (k0 + 16 < ke) {
                if (t < 64) aN = *(const float4*)(f.x + (long)(m0 + ar) * 1024 + (k0 + 16) + ak * 4);
                b0 = *(const float4*)(B + (long)(k0 + 16 + bk) * ldb + n0 + bn * 4);
                b1 = *(const float4*)(B + (long)(k0 + 16 + bk) * ldb + n0 + (bn + 8) * 4);
            }
            #pragma unroll
            for (int kk = 0; kk < 16; ++kk) {
                float2 a = *(float2*)&As[half][kk][ty * 2];
                float4 b = *(float4*)&Bs[half][kk][tx * 4];
                acc[0][0] += a.x * b.x; acc[0][1] += a.x * b.y;
                acc[0][2] += a.x * b.z; acc[0][3] += a.x * b.w;
                acc[1][0] += a.y * b.x; acc[1][1] += a.y * b.y;
                acc[1][2] += a.y * b.z; acc[1][3] += a.y * b.w;
            }
            __syncthreads();
        }
        #pragma unroll
        for (int i = 0; i < 2; ++i) {
            float4 v = make_float4(acc[i][0], acc[i][1], acc[i][2], acc[i][3]);
            *(float4*)(C + (long)(m0 + ty * 2 + i) * N + n0 + tx * 4) = v;
        }
    } else if (bx < 1616) {
        int b = bx - 1152;
        const float* srcs[7] = {f.wdkv, f.wdq, f.wkr, f.wuq, f.wqr, f.wuv, f.wout};
        unsigned short* dsts[7] = {f.wdkvT, f.wdqT, f.wkrT, f.wuqT, f.wqrT, f.wuvT, f.woutT};
        const int Ns[7]   = {256, 512, 32, 512, 256, 512, 1024};
        const int Klds[7] = {1024, 1024, 1024, 512, 512, 256, 512};
        const int Ntl[7]  = {4, 8, 1, 8, 4, 8, 16};
        const int bst[8]  = {0, 64, 192, 208, 272, 304, 336, 464};
        int e = 0;
        #pragma unroll
        for (int i = 1; i < 7; ++i) if (b >= bst[i]) e = i;
        int lb = b - bst[e];
        int nt = lb % Ntl[e], kt = lb / Ntl[e];
        const float* src = srcs[e];
        unsigned short* dst = dsts[e];
        int N = Ns[e], Kld = Klds[e];
        int k0 = kt * 64, n0 = nt * 64;
        int t = threadIdx.x;
        int c = t & 63, r4 = t >> 6;
        #pragma unroll
        for (int it = 0; it < 16; ++it) {
            int r = it * 4 + r4;
            float v = (n0 + c < N) ? src[(long)(k0 + r) * N + n0 + c] : 0.f;
            tile[r][c] = bfu(v);
        }
        __syncthreads();
        int wq = t & 7;
        #pragma unroll
        for (int itw = 0; itw < 2; ++itw) {
            int wr = itw * 32 + (t >> 3);
            if (n0 + wr < N) {
                unsigned short v[8];
                #pragma unroll
                for (int j = 0; j < 8; ++j) v[j] = tile[wq * 8 + j][wr];
                *(uint4*)(dst + (long)(n0 + wr) * Kld + k0 + wq * 8) = *(uint4*)v;
            }
        }
    } else if (bx < 1624) {
        int idx = (bx - 1616) * 256 + threadIdx.x;
        int j = idx >> 4, i = idx & 15;
        float rd = f.raw_delta[i];
        float delta = -6.283185307179586f * (1.f / (1.f + expf(-rd)));
        float th = exp2f(-(float)i * 0.83048202372184f);
        float ang = (float)j * th + delta;
        float sv, cv;
        sincosf(ang, &sv, &cv);
        f.csc[idx] = cv;
        f.css[idx] = sv;
    } else {
        int idx = (bx - 1624) * 256 + threadIdx.x;
        f.wukb[idx] = bfu(f.wuk[idx]);
    }
}

// ============ bf16 MFMA routed multi-GEMM (+ per-entry bf16 output) ==========
struct MFG {
    const float* A[10]; const unsigned short* B[10]; float* C[10];
    int lda[10], ldb[10], ldc[10], K[10], N[10], obf[10];
    int tstart[11]; int ne;
};

__global__ __launch_bounds__(256) void mgemm(MFG mg)
{
    int bx = blockIdx.x, e = 0;
    #pragma unroll
    for (int i = 1; i < 10; ++i) if (i < mg.ne && bx >= mg.tstart[i]) e = i;
    const float* A = mg.A[e];
    const unsigned short* B = mg.B[e];
    float* C = mg.C[e];
    int lda = mg.lda[e], ldb = mg.ldb[e], ldc = mg.ldc[e];
    int K = mg.K[e], N = mg.N[e];
    int m0 = blockIdx.y * 64, n0 = (bx - mg.tstart[e]) * 64;

    __shared__ unsigned short As[64][40];
    __shared__ unsigned short Bs[64][40];
    int t = threadIdx.x;
    int srow = t >> 2, skq = t & 3;
    int wid = t >> 6, l = t & 63;
    int wm = (wid >> 1) * 32, wn = (wid & 1) * 32;
    int fr = l & 15, fk = (l >> 4) * 8;
    bool bok = (n0 + srow) < N;

    f32x4 acc00 = {0.f, 0.f, 0.f, 0.f};
    f32x4 acc01 = {0.f, 0.f, 0.f, 0.f};
    f32x4 acc10 = {0.f, 0.f, 0.f, 0.f};
    f32x4 acc11 = {0.f, 0.f, 0.f, 0.f};

    for (int k0 = 0; k0 < K; k0 += 32) {
        {
            const float* ap = A + (long)(m0 + srow) * lda + k0 + skq * 8;
            float4 v0 = *(const float4*)ap;
            float4 v1 = *(const float4*)(ap + 4);
            unsigned short* d = &As[srow][skq * 8];
            d[0] = bfu(v0.x); d[1] = bfu(v0.y); d[2] = bfu(v0.z); d[3] = bfu(v0.w);
            d[4] = bfu(v1.x); d[5] = bfu(v1.y); d[6] = bfu(v1.z); d[7] = bfu(v1.w);
        }
        {
            uint4 bv = make_uint4(0u, 0u, 0u, 0u);
            if (bok) bv = *(const uint4*)(B + (long)(n0 + srow) * ldb + k0 + skq * 8);
            *(uint4*)&Bs[srow][skq * 8] = bv;
        }
        __syncthreads();
        bf16x8 a0 = *(bf16x8*)&As[wm + fr][fk];
        bf16x8 a1 = *(bf16x8*)&As[wm + 16 + fr][fk];
        bf16x8 b0 = *(bf16x8*)&Bs[wn + fr][fk];
        bf16x8 b1 = *(bf16x8*)&Bs[wn + 16 + fr][fk];
        acc00 = __builtin_amdgcn_mfma_f32_16x16x32_bf16(a0, b0, acc00, 0, 0, 0);
        acc01 = __builtin_amdgcn_mfma_f32_16x16x32_bf16(a0, b1, acc01, 0, 0, 0);
        acc10 = __builtin_amdgcn_mfma_f32_16x16x32_bf16(a1, b0, acc10, 0, 0, 0);
        acc11 = __builtin_amdgcn_mfma_f32_16x16x32_bf16(a1, b1, acc11, 0, 0, 0);
        __syncthreads();
    }
    int crow = (l >> 4) * 4;
    int col0 = n0 + wn + fr, col1 = n0 + wn + 16 + fr;
    if (mg.obf[e]) {
        unsigned short* Cu = (unsigned short*)C;
        if (col0 < N) {
            #pragma unroll
            for (int r = 0; r < 4; ++r) {
                Cu[(long)(m0 + wm + crow + r) * ldc + col0]      = bfu(acc00[r]);
                Cu[(long)(m0 + wm + 16 + crow + r) * ldc + col0] = bfu(acc10[r]);
            }
        }
        if (col1 < N) {
            #pragma unroll
            for (int r = 0; r < 4; ++r) {
                Cu[(long)(m0 + wm + crow + r) * ldc + col1]      = bfu(acc01[r]);
                Cu[(long)(m0 + wm + 16 + crow + r) * ldc + col1] = bfu(acc11[r]);
            }
        }
    } else {
        if (col0 < N) {
            #pragma unroll
            for (int r = 0; r < 4; ++r) {
                C[(long)(m0 + wm + crow + r) * ldc + col0]      = acc00[r];
                C[(long)(m0 + wm + 16 + crow + r) * ldc + col0] = acc10[r];
            }
        }
        if (col1 < N) {
            #pragma unroll
            for (int r = 0; r < 4; ++r) {
                C[(long)(m0 + wm + crow + r) * ldc + col1]      = acc01[r];
                C[(long)(m0 + wm + 16 + crow + r) * ldc + col1] = acc11[r];
            }
        }
    }
}

// ============ MID mega-kernel: indexer + qabs GEMM + pope + mu ===============
struct MIDARG {
    const float *qIP, *kIP, *w_idx; float* I;
    const float* qc; const unsigned short* wukb; float* qabs;
    const float *qrp, *raw_delta; float* qrr;
    const float* xkr; float* mu;
};

__global__ __launch_bounds__(256) void mid_kernel(MIDARG g)
{
    __shared__ __align__(16) char smem[26112];
    int b = blockIdx.x;
    int t = threadIdx.x;
    if (b < 512) {
        int sb = b % 16, tb = b / 16;
        if (sb * 64 > tb * 32 + 31) return;
        int t0 = tb * 32, s0 = sb * 64;
        float (*ksT)[68] = (float(*)[68])smem;
        float (*qs)[68]  = (float(*)[68])(smem + 17408);
        {
            int r = t & 63, q = t >> 6;
            #pragma unroll
            for (int u = 0; u < 4; ++u) {
                int c4 = q * 4 + u;
                long off = (long)(s0 + r) * 64 + c4 * 4;
                float4 v = *(const float4*)(g.kIP + off);
                #pragma unroll
                for (int s = 1; s < 4; ++s) {
                    float4 v2 = *(const float4*)(g.kIP + (long)s * 65536 + off);
                    v.x += v2.x; v.y += v2.y; v.z += v2.z; v.w += v2.w;
                }
                ksT[c4 * 4 + 0][r] = v.x;
                ksT[c4 * 4 + 1][r] = v.y;
                ksT[c4 * 4 + 2][r] = v.z;
                ksT[c4 * 4 + 3][r] = v.w;
            }
        }
        int ty = t >> 4, tx = t & 15;
        float accI[2][4] = {};
        for (int h = 0; h < 8; ++h) {
            __syncthreads();
            {
                int r = t >> 3, q = t & 7;
                long base = (long)(t0 + r) * 512 + h * 64;
                #pragma unroll
                for (int half = 0; half < 2; ++half) {
                    long off = base + (q + half * 8) * 4;
                    float4 a = *(const float4*)(g.qIP + off);
                    #pragma unroll
                    for (int s = 1; s < 4; ++s) {
                        float4 a1 = *(const float4*)(g.qIP + (long)s * 524288 + off);
                        a.x += a1.x; a.y += a1.y; a.z += a1.z; a.w += a1.w;
                    }
                    *(float4*)&qs[r][(q + half * 8) * 4] = a;
                }
            }
            __syncthreads();
            float acc[2][4] = {};
            #pragma unroll
            for (int dc = 0; dc < 4; ++dc) {
                float a0[16], a1[16];
                #pragma unroll
                for (int u = 0; u < 4; ++u) {
                    float4 v0 = *(float4*)&qs[ty * 2][dc * 16 + u * 4];
                    float4 v1 = *(float4*)&qs[ty * 2 + 1][dc * 16 + u * 4];
                    a0[u * 4 + 0] = v0.x; a0[u * 4 + 1] = v0.y; a0[u * 4 + 2] = v0.z; a0[u * 4 + 3] = v0.w;
                    a1[u * 4 + 0] = v1.x; a1[u * 4 + 1] = v1.y; a1[u * 4 + 2] = v1.z; a1[u * 4 + 3] = v1.w;
                }
                #pragma unroll
                for (int kk = 0; kk < 16; ++kk) {
                    int d = dc * 16 + kk;
                    float4 bb = *(float4*)&ksT[d][tx * 4];
                    acc[0][0] += a0[kk] * bb.x; acc[0][1] += a0[kk] * bb.y;
                    acc[0][2] += a0[kk] * bb.z; acc[0][3] += a0[kk] * bb.w;
                    acc[1][0] += a1[kk] * bb.x; acc[1][1] += a1[kk] * bb.y;
                    acc[1][2] += a1[kk] * bb.z; acc[1][3] += a1[kk] * bb.w;
                }
            }
            float wh = g.w_idx[h];
            #pragma unroll
            for (int i = 0; i < 2; ++i)
                #pragma unroll
                for (int j = 0; j < 4; ++j)
                    accI[i][j] += wh * fmaxf(acc[i][j], 0.f);
        }
        #pragma unroll
        for (int i = 0; i < 2; ++i) {
            float4 v = make_float4(accI[i][0], accI[i][1], accI[i][2], accI[i][3]);
            *(float4*)&g.I[(long)(t0 + ty * 2 + i) * 1024 + s0 + tx * 4] = v;
        }
    } else if (b < 1024) {
        int lb = b - 512;
        int h = lb >> 6, rem = lb & 63;
        int n0 = (rem >> 4) * 64, m0 = (rem & 15) * 64;
        const float* A = g.qc + h * 64;
        const unsigned short* B = g.wukb + h * 64;
        float* C = g.qabs + h * 256;
        unsigned short (*As)[40] = (unsigned short(*)[40])smem;
        unsigned short (*Bs)[40] = (unsigned short(*)[40])(smem + 5120);
        int srow = t >> 2, skq = t & 3;
        int wid = t >> 6, l = t & 63;
        int wm = (wid >> 1) * 32, wn = (wid & 1) * 32;
        int fr = l & 15, fk = (l >> 4) * 8;
        f32x4 acc00 = {0.f, 0.f, 0.f, 0.f};
        f32x4 acc01 = {0.f, 0.f, 0.f, 0.f};
        f32x4 acc10 = {0.f, 0.f, 0.f, 0.f};
        f32x4 acc11 = {0.f, 0.f, 0.f, 0.f};
        for (int k0 = 0; k0 < 64; k0 += 32) {
            {
                const float* ap = A + (long)(m0 + srow) * 512 + k0 + skq * 8;
                float4 v0 = *(const float4*)ap;
                float4 v1 = *(const float4*)(ap + 4);
                unsigned short* d = &As[srow][skq * 8];
                d[0] = bfu(v0.x); d[1] = bfu(v0.y); d[2] = bfu(v0.z); d[3] = bfu(v0.w);
                d[4] = bfu(v1.x); d[5] = bfu(v1.y); d[6] = bfu(v1.z); d[7] = bfu(v1.w);
            }
            {
                uint4 bv = *(const uint4*)(B + (long)(n0 + srow) * 512 + k0 + skq * 8);
                *(uint4*)&Bs[srow][skq * 8] = bv;
            }
            __syncthreads();
            bf16x8 a0 = *(bf16x8*)&As[wm + fr][fk];
            bf16x8 a1 = *(bf16x8*)&As[wm + 16 + fr][fk];
            bf16x8 b0 = *(bf16x8*)&Bs[wn + fr][fk];
            bf16x8 b1 = *(bf16x8*)&Bs[wn + 16 + fr][fk];
            acc00 = __builtin_amdgcn_mfma_f32_16x16x32_bf16(a0, b0, acc00, 0, 0, 0);
            acc01 = __builtin_amdgcn_mfma_f32_16x16x32_bf16(a0, b1, acc01, 0, 0, 0);
            acc10 = __builtin_amdgcn_mfma_f32_16x16x32_bf16(a1, b0, acc10, 0, 0, 0);
            acc11 = __builtin_amdgcn_mfma_f32_16x16x32_bf16(a1, b1, acc11, 0, 0, 0);
            __syncthreads();
        }
        int crow = (l >> 4) * 4;
        int col0 = n0 + wn + fr, col1 = n0 + wn + 16 + fr;
        #pragma unroll
        for (int r = 0; r < 4; ++r) {
            C[(long)(m0 + wm + crow + r) * 2048 + col0]      = acc00[r];
            C[(long)(m0 + wm + 16 + crow + r) * 2048 + col0] = acc10[r];
            C[(long)(m0 + wm + crow + r) * 2048 + col1]      = acc01[r];
            C[(long)(m0 + wm + 16 + crow + r) * 2048 + col1] = acc11[r];
        }
    } else if (b < 1536) {
        int tq = (b - 1024) * 2 + (t >> 7);
        int tt = t & 127;
        int h = tt >> 4, i = tt & 15;
        float rd = g.raw_delta[i];
        float delta = -6.283185307179586f * (1.f / (1.f + expf(-rd)));
        float th = exp2f(-(float)i * 0.83048202372184f);
        float ang = (float)tq * th + delta;
        float sv, cv;
        sincosf(ang, &sv, &cv);
        float m1 = sp_softplus(g.qrp[tq * 256 + h * 32 + i]);
        float m2 = sp_softplus(g.qrp[tq * 256 + h * 32 + 16 + i]);
        g.qrr[tq * 256 + h * 32 + i]      = m1 * cv - m2 * sv;
        g.qrr[tq * 256 + h * 32 + 16 + i] = m1 * sv + m2 * cv;
    } else {
        int i = (b - 1536) * 256 + t;
        g.mu[i] = sp_softplus(g.xkr[i]);
    }
}

// -------- exact top-k: full wave bitonic sort (unchanged from r11) -----------
__global__ __launch_bounds__(256) void topk_kernel(
    const float* __restrict__ I, int* __restrict__ idxout)
{
    int t = blockIdx.x * 4 + (threadIdx.x >> 6);
    int lane = threadIdx.x & 63;
    int smin = max(0, t - 63);
    int w = min(64, t + 1);
    if (lane < w) idxout[t * 128 + lane] = smin + lane;
    for (int q = t + 1 + lane; q < 128; q += 64)
        idxout[t * 128 + q] = q;
    int f = max(0, t - 63);
    int m = min(f, 64);
    if (m == 0) return;
    const float* row = I + (long)t * 1024;

    unsigned long long key[16];
    #pragma unroll
    for (int g4 = 0; g4 < 4; ++g4) {
        float4 v = *(const float4*)(row + lane * 16 + g4 * 4);
        float vv[4] = {v.x, v.y, v.z, v.w};
        #pragma unroll
        for (int j = 0; j < 4; ++j) {
            int s = lane * 16 + g4 * 4 + j;
            unsigned long long k = 0ull;
            if (s < f) {
                unsigned u = __float_as_uint(vv[j]);
                unsigned ou = (u & 0x80000000u) ? ~u : (u | 0x80000000u);
                k = ((unsigned long long)ou << 32) | (0xFFFFFFFFu - (unsigned)s);
            }
            key[g4 * 4 + j] = k;
        }
    }

    #pragma unroll
    for (int km = 1; km <= 10; ++km) {
        #pragma unroll
        for (int jm = km - 1; jm >= 0; --jm) {
            if (jm >= 4) {
                int lmask = 1 << (jm - 4);
                #pragma unroll
                for (int r = 0; r < 16; ++r) {
                    unsigned long long other = __shfl_xor(key[r], lmask, 64);
                    int i = lane * 16 + r;
                    bool keep_max = (((i & (1 << km)) == 0) == ((i & (1 << jm)) == 0));
                    unsigned long long mx = key[r] > other ? key[r] : other;
                    unsigned long long mn = key[r] > other ? other : key[r];
                    key[r] = keep_max ? mx : mn;
                }
            } else {
                int rmask = 1 << jm;
                #pragma unroll
                for (int r = 0; r < 16; ++r) {
                    if ((r & rmask) == 0) {
                        int r2 = r | rmask;
                        int i = lane * 16 + r;
                        bool keep_max_low = ((i & (1 << km)) == 0);
                        unsigned long long a = key[r], b = key[r2];
                        unsigned long long mx = a > b ? a : b;
                        unsigned long long mn = a > b ? b : a;
                        key[r]  = keep_max_low ? mx : mn;
                        key[r2] = keep_max_low ? mn : mx;
                    }
                }
            }
        }
    }

    if (lane < 4) {
        #pragma unroll
        for (int r = 0; r < 16; ++r) {
            int e = lane * 16 + r;
            if (e < m) {
                int s = (int)(0xFFFFFFFFu - (unsigned)(key[r] & 0xFFFFFFFFull));
                idxout[t * 128 + w + e] = s;
            }
        }
    }
}

// -------- fused attention v8: LDS-minimal (global-direct QK frags + PV) ------
// 256 threads (4 waves), block per query t. LDS ~2.8 KB -> 8 blocks/CU if
// VGPR <= 64 (K-loop unroll 1, Q-frags streamed). Numerically bit-identical
// to v7: same bytes (ckvb), same kr/Q formulas + bfu points, same MFMA
// order (ks 0..8), same softmax and PV accumulation order.
__global__ __launch_bounds__(256) void attn_kernel(
    const float* __restrict__ qabs, const float* __restrict__ qrr,
    const unsigned short* __restrict__ ckvb, const float* __restrict__ mu,
    const float* __restrict__ csc, const float* __restrict__ css,
    const int* __restrict__ idxb, float* __restrict__ olat)
{
    __shared__ float sc[8][68];
    __shared__ float hs[16];
    __shared__ int idx_s[128];

    int t = blockIdx.x, tid = threadIdx.x;
    int w = tid >> 6, l = tid & 63;
    const float scale = 0.10206207261596575f;

    if (tid < 128) idx_s[tid] = idxb[t * 128 + tid];

    int hrow = l & 15;             // MFMA A-row / B-col lane index
    int kslice = (l >> 4) * 8;     // k-slice within K=32
    int hpv = l >> 3;              // PV head
    int c8 = w * 64 + (l & 7) * 8; // PV c-octet

    float mrun0 = -INFINITY, mrun1 = -INFINITY;
    float lrun0 = 0.f, lrun1 = 0.f;
    float acc0 = 0, acc1 = 0, acc2 = 0, acc3 = 0;
    float acc4 = 0, acc5 = 0, acc6 = 0, acc7 = 0;

    __syncthreads();

    #pragma unroll
    for (int chunk = 0; chunk < 2; ++chunk) {
        if (chunk) __syncthreads();       // all waves done with prev PV (sc reuse)

        // ---- QK^T via MFMA, operands streamed from L2
        int r = w * 16 + hrow;            // slot-in-chunk
        int src = idx_s[chunk * 64 + r];
        int jglob = chunk * 64 + r;
        f32x4 st = {0.f, 0.f, 0.f, 0.f};
        #pragma unroll 1
        for (int ks = 0; ks < 8; ++ks) {  // unroll 1: cap VGPR for occupancy
            bf16x8 af = *(const bf16x8*)(ckvb + (long)src * 256 + ks * 32 + kslice);
            bf16x8 qf = {0, 0, 0, 0, 0, 0, 0, 0};
            if (hrow < 8) {
                const float* qp = qabs + (long)t * 2048 + hrow * 256 + ks * 32 + kslice;
                float4 a = *(const float4*)qp;
                float4 b = *(const float4*)(qp + 4);
                unsigned short qq[8];
                qq[0] = bfu(a.x * scale); qq[1] = bfu(a.y * scale);
                qq[2] = bfu(a.z * scale); qq[3] = bfu(a.w * scale);
                qq[4] = bfu(b.x * scale); qq[5] = bfu(b.y * scale);
                qq[6] = bfu(b.z * scale); qq[7] = bfu(b.w * scale);
                qf = *(bf16x8*)qq;
            }
            st = __builtin_amdgcn_mfma_f32_16x16x32_bf16(af, qf, st, 0, 0, 0);
        }
        {   // ks = 8: rope part — kr computed on the fly (same formula/bfu as v7)
            int i15 = kslice & 15;
            bool lo = kslice < 16;
            float4 m1a = *(const float4*)(mu + src * 32 + i15);
            float4 m1b = *(const float4*)(mu + src * 32 + i15 + 4);
            float4 m2a = *(const float4*)(mu + src * 32 + 16 + i15);
            float4 m2b = *(const float4*)(mu + src * 32 + 16 + i15 + 4);
            float4 ca = *(const float4*)(csc + jglob * 16 + i15);
            float4 cb = *(const float4*)(csc + jglob * 16 + i15 + 4);
            float4 sa = *(const float4*)(css + jglob * 16 + i15);
            float4 sb = *(const float4*)(css + jglob * 16 + i15 + 4);
            unsigned short hh[8];
            hh[0] = bfu(lo ? m1a.x * ca.x - m2a.x * sa.x : m1a.x * sa.x + m2a.x * ca.x);
            hh[1] = bfu(lo ? m1a.y * ca.y - m2a.y * sa.y : m1a.y * sa.y + m2a.y * ca.y);
            hh[2] = bfu(lo ? m1a.z * ca.z - m2a.z * sa.z : m1a.z * sa.z + m2a.z * ca.z);
            hh[3] = bfu(lo ? m1a.w * ca.w - m2a.w * sa.w : m1a.w * sa.w + m2a.w * ca.w);
            hh[4] = bfu(lo ? m1b.x * cb.x - m2b.x * sb.x : m1b.x * sb.x + m2b.x * cb.x);
            hh[5] = bfu(lo ? m1b.y * cb.y - m2b.y * sb.y : m1b.y * sb.y + m2b.y * cb.y);
            hh[6] = bfu(lo ? m1b.z * cb.z - m2b.z * sb.z : m1b.z * sb.z + m2b.z * cb.z);
            hh[7] = bfu(lo ? m1b.w * cb.w - m2b.w * sb.w : m1b.w * sb.w + m2b.w * cb.w);
            bf16x8 af = *(bf16x8*)hh;
            bf16x8 qf = {0, 0, 0, 0, 0, 0, 0, 0};
            if (hrow < 8) {
                const float* qp = qrr + (long)t * 256 + hrow * 32 + kslice;
                float4 a = *(const float4*)qp;
                float4 b = *(const float4*)(qp + 4);
                unsigned short qq[8];
                qq[0] = bfu(a.x * scale); qq[1] = bfu(a.y * scale);
                qq[2] = bfu(a.z * scale); qq[3] = bfu(a.w * scale);
                qq[4] = bfu(b.x * scale); qq[5] = bfu(b.y * scale);
                qq[6] = bfu(b.z * scale); qq[7] = bfu(b.w * scale);
                qf = *(bf16x8*)qq;
            }
            st = __builtin_amdgcn_mfma_f32_16x16x32_bf16(af, qf, st, 0, 0, 0);
        }
        {   // scatter S^T to sc[h][slot] (h<8 only)
            int srow2 = w * 16 + (l >> 4) * 4;
            if (hrow < 8) {
                #pragma unroll
                for (int rr = 0; rr < 4; ++rr) sc[hrow][srow2 + rr] = st[rr];
            }
        }
        __syncthreads();

        // ---- online softmax: wave w handles heads 2w, 2w+1 (identical to v7)
        float rh0, rh1;
        {
            int h = 2 * w;
            float v = sc[h][l];
            float mx = v;
            #pragma unroll
            for (int off = 32; off > 0; off >>= 1) mx = fmaxf(mx, __shfl_xor(mx, off));
            float mnew = fmaxf(mrun0, mx);
            float p = expf(v - mnew);
            float ps = p;
            #pragma unroll
            for (int off = 32; off > 0; off >>= 1) ps += __shfl_xor(ps, off);
            rh0 = expf(mrun0 - mnew);
            lrun0 = lrun0 * rh0 + ps;
            mrun0 = mnew;
            sc[h][l] = p;
        }
        {
            int h = 2 * w + 1;
            float v = sc[h][l];
            float mx = v;
            #pragma unroll
            for (int off = 32; off > 0; off >>= 1) mx = fmaxf(mx, __shfl_xor(mx, off));
            float mnew = fmaxf(mrun1, mx);
            float p = expf(v - mnew);
            float ps = p;
            #pragma unroll
            for (int off = 32; off > 0; off >>= 1) ps += __shfl_xor(ps, off);
            rh1 = expf(mrun1 - mnew);
            lrun1 = lrun1 * rh1 + ps;
            mrun1 = mnew;
            sc[h][l] = p;
        }
        if (l == 0) {
            hs[2 * w] = rh0;
            hs[2 * w + 1] = rh1;
            if (chunk == 1) {
                hs[8 + 2 * w] = lrun0;
                hs[8 + 2 * w + 1] = lrun1;
            }
        }
        __syncthreads();

        // ---- PV (VALU): V streamed from L2; 8 lanes/address coalesce to one req
        float rsel = hs[hpv];
        acc0 *= rsel; acc1 *= rsel; acc2 *= rsel; acc3 *= rsel;
        acc4 *= rsel; acc5 *= rsel; acc6 *= rsel; acc7 *= rsel;
        #pragma unroll 4
        for (int j = 0; j < 64; ++j) {
            float p = sc[hpv][j];
            int srcj = idx_s[chunk * 64 + j];
            uint4 vv = *(const uint4*)(ckvb + (long)srcj * 256 + c8);
            acc0 += p * __uint_as_float(vv.x << 16);
            acc1 += p * __uint_as_float(vv.x & 0xffff0000u);
            acc2 += p * __uint_as_float(vv.y << 16);
            acc3 += p * __uint_as_float(vv.y & 0xffff0000u);
            acc4 += p * __uint_as_float(vv.z << 16);
            acc5 += p * __uint_as_float(vv.z & 0xffff0000u);
            acc6 += p * __uint_as_float(vv.w << 16);
            acc7 += p * __uint_as_float(vv.w & 0xffff0000u);
        }
    }

    float inv = 1.f / hs[8 + hpv];
    float* op = olat + (long)t * 2048 + hpv * 256 + c8;
    *(float4*)op       = make_float4(acc0 * inv, acc1 * inv, acc2 * inv, acc3 * inv);
    *(float4*)(op + 4) = make_float4(acc4 * inv, acc5 * inv, acc6 * inv, acc7 * inv);
}

extern "C" void kernel_launch(void* const* d_in, const int* in_sizes, int n_in,
                              void* d_out, int out_size, void* d_ws, size_t ws_size,
                              hipStream_t stream)
{
    const float* x         = (const float*)d_in[0];
    const float* w_q_idx   = (const float*)d_in[1];
    const float* w_k_idx   = (const float*)d_in[2];
    const float* w_idx     = (const float*)d_in[3];
    const float* raw_delta = (const float*)d_in[4];
    const float* w_dkv     = (const float*)d_in[5];
    const float* w_uk      = (const float*)d_in[6];
    const float* w_uv      = (const float*)d_in[7];
    const float* w_dq      = (const float*)d_in[8];
    const float* w_uq      = (const float*)d_in[9];
    const float* w_qr      = (const float*)d_in[10];
    const float* w_kr      = (const float*)d_in[11];
    const float* w_out     = (const float*)d_in[12];
    (void)in_sizes; (void)n_in; (void)out_size; (void)ws_size;
    float* out = (float*)d_out;

    float* ws = (float*)d_ws;
    unsigned short* ckvb = (unsigned short*)ws;   ws += 131072;   // 1024x256 bf16
    float* cq    = ws;        ws += 1024 * 512;
    float* xkr   = ws;        ws += 1024 * 32;
    float* qrp   = ws;        ws += 1024 * 256;
    float* qrr   = ws;        ws += 1024 * 256;
    float* qc    = ws;        ws += 1024 * 512;
    float* qabs  = ws;        ws += 1024 * 2048;
    float* Ibuf  = ws;        ws += 1024 * 1024;
    int*   idxb  = (int*)ws;  ws += 1024 * 128;
    float* olat  = ws;        ws += 1024 * 2048;
    float* outh  = ws;        ws += 1024 * 512;
    float* mu    = ws;        ws += 1024 * 32;
    float* cscb  = ws;        ws += 128 * 16;
    float* cssb  = ws;        ws += 128 * 16;
    unsigned short* wdkvT = (unsigned short*)ws;  ws += 131072;
    unsigned short* wdqT  = (unsigned short*)ws;  ws += 262144;
    unsigned short* wkrT  = (unsigned short*)ws;  ws += 16384;
    unsigned short* wuqT  = (unsigned short*)ws;  ws += 131072;
    unsigned short* wqrT  = (unsigned short*)ws;  ws += 65536;
    unsigned short* wuvT  = (unsigned short*)ws;  ws += 65536;
    unsigned short* woutT = (unsigned short*)ws;  ws += 262144;
    unsigned short* wukb  = (unsigned short*)ws;  ws += 65536;
    float* part  = ws;        ws += 2359296;
    float* qIP = part;                  // 4 x 524288
    float* kIP = part + 2097152;        // 4 x 65536

    // ---- L1: FRONT (sel GEMM + weight tcast + cs + wukb)
    {
        FRONT f{};
        f.x = x; f.wqidx = w_q_idx; f.wkidx = w_k_idx; f.raw_delta = raw_delta; f.wuk = w_uk;
        f.wdkv = w_dkv; f.wdq = w_dq; f.wkr = w_kr; f.wuq = w_uq; f.wqr = w_qr;
        f.wuv = w_uv; f.wout = w_out;
        f.qIP = qIP; f.kIP = kIP; f.csc = cscb; f.css = cssb;
        f.wdkvT = wdkvT; f.wdqT = wdqT; f.wkrT = wkrT; f.wuqT = wuqT;
        f.wqrT = wqrT; f.wuvT = wuvT; f.woutT = woutT; f.wukb = wukb;
        front_kernel<<<dim3(2136), dim3(256), 0, stream>>>(f);
    }

    // ---- L2: stage-1 value projections: ckv (bf16 out), cq, xkr
    {
        MFG m{};
        for (int i = 0; i < 3; ++i) { m.A[i]=x; m.lda[i]=1024; m.K[i]=1024; }
        m.B[0]=wdkvT; m.C[0]=(float*)ckvb; m.ldb[0]=1024; m.ldc[0]=256; m.N[0]=256; m.obf[0]=1;
        m.B[1]=wdqT;  m.C[1]=cq;           m.ldb[1]=1024; m.ldc[1]=512; m.N[1]=512;
        m.B[2]=wkrT;  m.C[2]=xkr;          m.ldb[2]=1024; m.ldc[2]=32;  m.N[2]=32;
        m.tstart[0]=0; m.tstart[1]=4; m.tstart[2]=12; m.tstart[3]=13;
        m.ne = 3;
        mgemm<<<dim3(13, 16), dim3(256), 0, stream>>>(m);
    }

    // ---- L3: stage-2: qc, qrp
    {
        MFG m{};
        for (int i = 0; i < 2; ++i) { m.A[i]=cq; m.lda[i]=512; m.K[i]=512; }
        m.B[0]=wuqT; m.C[0]=qc;  m.ldb[0]=512; m.ldc[0]=512; m.N[0]=512;
        m.B[1]=wqrT; m.C[1]=qrp; m.ldb[1]=512; m.ldc[1]=256; m.N[1]=256;
        m.tstart[0]=0; m.tstart[1]=8; m.tstart[2]=12;
        m.ne = 2;
        mgemm<<<dim3(12, 16), dim3(256), 0, stream>>>(m);
    }

    // ---- L4: MID (indexer + qabs + pope + mu)
    {
        MIDARG g{};
        g.qIP = qIP; g.kIP = kIP; g.w_idx = w_idx; g.I = Ibuf;
        g.qc = qc; g.wukb = wukb; g.qabs = qabs;
        g.qrp = qrp; g.raw_delta = raw_delta; g.qrr = qrr;
        g.xkr = xkr; g.mu = mu;
        mid_kernel<<<dim3(1664), dim3(256), 0, stream>>>(g);
    }

    // ---- L5: exact top-k (bitonic)
    topk_kernel<<<dim3(256), dim3(256), 0, stream>>>(Ibuf, idxb);

    // ---- L6: fused attention v8 -> olat
    attn_kernel<<<dim3(1024), dim3(256), 0, stream>>>(qabs, qrr, ckvb, mu, cscb, cssb, idxb, olat);

    // ---- L7: outh_h = olat_h @ w_uv_h
    {
        MFG m{};
        for (int h = 0; h < 8; ++h) {
            m.A[h] = olat + h * 256;      m.lda[h] = 2048; m.K[h] = 256;
            m.B[h] = wuvT + h * 64 * 256; m.ldb[h] = 256;
            m.C[h] = outh + h * 64;       m.ldc[h] = 512;  m.N[h] = 64;
            m.tstart[h] = h;
        }
        m.tstart[8] = 8;
        m.ne = 8;
        mgemm<<<dim3(8, 16), dim3(256), 0, stream>>>(m);
    }

    // ---- L8: out = outh @ w_out
    {
        MFG m{};
        m.A[0] = outh;  m.lda[0] = 512; m.K[0] = 512;
        m.B[0] = woutT; m.ldb[0] = 512;
        m.C[0] = out;   m.ldc[0] = 1024; m.N[0] = 1024;
        m.tstart[0] = 0; m.tstart[1] = 16;
        m.ne = 1;
        mgemm<<<dim3(16, 16), dim3(256), 0, stream>>>(m);
    }
}